// Round 8
// baseline (773.439 us; speedup 1.0000x reference)
//
#include <hip/hip_runtime.h>
#include <math.h>

#ifndef M_PI
#define M_PI 3.14159265358979323846
#endif

#define BB 4
#define TT 500
#define NSAMP 120000
#define NHARM 32
#define NFFT 256
#define NBIN 129
#define NHOPF 64
#define NFRAMES 1876
#define HID 64
#define MLPD 128
#define FEATD 88

#define R_MAG ((float)(500.0/1876.0))
#define R_UP_F ((float)(500.0/120000.0))

// ---- workspace layout (float offsets) ----
#define OFF_HARML 0
#define OFF_HARMR 64000
#define OFF_AMP   128000
#define OFF_NMAGL 130000
#define OFF_NMAGR 388000
#define OFF_C1    646000            /* 128 floats: RN32(c32*mf32) per (b,k) */
#define OFF_TRUNK 646128
#define OFF_FEAT  (OFF_TRUNK)
#define OFF_H1    (OFF_FEAT+176000)
#define OFF_H2    (OFF_H1+256000)
#define OFF_GI    (OFF_H2+256000)
#define OFF_GOUT  (OFF_GI+384000)
#define OFF_POST  (OFF_GOUT+128000)
/* spec reuses trunk region (trunk dead after k_heads) */
#define OFF_SPECL (OFF_TRUNK)
#define OFF_SPECR (OFF_SPECL+1936032)
#define OFF_FRL   (OFF_SPECR+1936032)
#define OFF_FRR   (OFF_FRL+1921024)
/* total = 8360240 floats = 33.44 MB */

// f32 upsample position/interp chain, bit-exact to numpy float32 elementwise
__device__ __forceinline__ void up_coords(int m, int* i0, int* i1, float* w, float* w1){
  float pos = __fadd_rn(__fmul_rn(__fadd_rn((float)m, 0.5f), R_UP_F), -0.5f);
  pos = fminf(fmaxf(pos, 0.0f), 499.0f);
  int a = (int)pos;
  *i0 = a; *i1 = min(a+1, TT-1);
  float ww = __fsub_rn(pos, (float)a);
  *w = ww; *w1 = __fsub_rn(1.0f, ww);
}
__device__ __forceinline__ float f0_up_elem(const float* __restrict__ f0s, int m){
  int i0,i1; float w,w1;
  up_coords(m,&i0,&i1,&w,&w1);
  return __fadd_rn(__fmul_rn(f0s[i0], w1), __fmul_rn(f0s[i1], w));
}

// ---------------- encoding ----------------
__global__ void k_enc(const float* __restrict__ f0, const float* __restrict__ ldb,
                      const float* __restrict__ vel, float* __restrict__ feat){
  int idx = blockIdx.x*blockDim.x + threadIdx.x;
  if (idx >= BB*TT) return;
  int b = idx / TT;
  float f = f0[idx];
  float gate = (f > 0.0f) ? 1.0f : 0.0f;
  float fs = fmaxf(f, 20.0f);
  float fn = (logf(fs) - (float)2.995732273553991) / (float)5.5214609178622464;
  fn = fminf(fmaxf(fn, 0.0f), 1.0f);
  float ln = fminf(fmaxf((ldb[idx] + 80.0f) / 80.0f, 0.0f), 1.0f);
  float vn = fminf(fmaxf(vel[b] / 7.0f, 0.0f), 1.0f);
  float* o = feat + idx*FEATD;
  #pragma unroll 4
  for (int i=1;i<=32;i++){
    float ang = (float)M_PI * (float)i * fn;
    o[2*i-2] = sinf(ang)*gate;
    o[2*i-1] = cosf(ang)*gate;
  }
  #pragma unroll
  for (int i=1;i<=8;i++){
    float ang = (float)M_PI * (float)i * ln;
    o[64+2*i-2] = sinf(ang);
    o[64+2*i-1] = cosf(ang);
  }
  #pragma unroll
  for (int i=1;i<=4;i++){
    float ang = (float)M_PI * (float)i * vn;
    o[80+2*i-2] = sinf(ang);
    o[80+2*i-1] = cosf(ang);
  }
}

// ---------------- generic matmul: out = act(in @ W^T + b) ----------------
template<int ACT>
__global__ void k_mm(const float* __restrict__ in, const float* __restrict__ W,
                     const float* __restrict__ bias, float* __restrict__ out,
                     int R, int C, int IN){
  int idx = blockIdx.x*blockDim.x + threadIdx.x;
  if (idx >= R*C) return;
  int r = idx / C, c = idx - r*C;
  const float* ip = in + r*IN;
  const float* wp = W + c*IN;
  float acc = bias[c];
  #pragma unroll 8
  for (int i=0;i<IN;i++) acc = fmaf(ip[i], wp[i], acc);
  if (ACT==1) acc = fmaxf(acc, 0.0f);
  out[idx] = acc;
}

// ---------------- GRU recurrence (gi precomputed) ----------------
// 3 waves/block: wave g computes gate g's dot for all 64 outputs (lane j ->
// output j, 64 weights/lane, ~84 VGPR -> never spills). h[j] is tracked
// REDUNDANTLY in a register on every wave; the dot broadcasts h[i] via
// v_readlane (register->SGPR, no LDS). Gate results cross waves through a
// double-buffered ash[2][192] -> exactly ONE barrier per step. All waves
// redundantly compute the activation chain (no serial wave-0 section).
// Dot keeps the exact sequential i=0..63 fmaf chain -> bit-identical.
__global__ __launch_bounds__(192,1) void k_gru(const float* __restrict__ gi,
    const float* __restrict__ Whh, const float* __restrict__ bhh,
    float* __restrict__ gout){
  int b = blockIdx.x;
  int tid = threadIdx.x;        // 0..191
  int g = tid >> 6;             // gate index = wave index
  int j = tid & 63;
  float w[64];
  #pragma unroll
  for (int i=0;i<16;i++){
    float4 v = *(const float4*)(Whh + (size_t)(g*64+j)*64 + i*4);
    w[4*i]=v.x; w[4*i+1]=v.y; w[4*i+2]=v.z; w[4*i+3]=v.w;
  }
  __shared__ float ash[2][192];
  float br = bhh[j], bz = bhh[64+j], bn = bhh[128+j];
  const float* gp = gi + (size_t)b*TT*192 + j;
  float* op = gout + (size_t)b*TT*64 + j;
  float hreg = 0.0f;            // h[j], redundant on all 3 waves
  float gr = gp[0], gz = gp[64], gn = gp[128];
  for (int t=0;t<TT;t++){
    // prefetch next step's gate inputs (latency hides under the dot)
    int tn = min(t+1, TT-1);
    float gr2 = gp[tn*192], gz2 = gp[tn*192+64], gn2 = gp[tn*192+128];
    // dot(w, h): h[i] broadcast by readlane; exact sequential i=0..63 chain
    float acc = 0.f;
    #pragma unroll
    for (int i=0;i<64;i++){
      float hi = __uint_as_float(__builtin_amdgcn_readlane(__float_as_uint(hreg), i));
      acc = fmaf(w[i], hi, acc);
    }
    ash[t&1][tid] = acc;
    __syncthreads();            // single barrier per step (dbuf makes it safe)
    float ar = ash[t&1][j], az = ash[t&1][64+j], an = ash[t&1][128+j];
    float r = 1.0f/(1.0f+expf(-(gr+ar+br)));
    float z = 1.0f/(1.0f+expf(-(gz+az+bz)));
    float n = tanhf(gn + r*(an+bn));
    hreg = (1.0f - z)*n + z*hreg;
    if (g==0) op[t*64] = hreg;
    gr=gr2; gz=gz2; gn=gn2;
  }
}

// ---------------- heads ----------------
__global__ void k_heads(const float* __restrict__ post,
  const float* __restrict__ WhL, const float* __restrict__ bhL,
  const float* __restrict__ WhR, const float* __restrict__ bhR,
  const float* __restrict__ Wam, const float* __restrict__ bam,
  const float* __restrict__ WnL, const float* __restrict__ bnL,
  const float* __restrict__ WnR, const float* __restrict__ bnR,
  float* __restrict__ harmL, float* __restrict__ harmR, float* __restrict__ amp,
  float* __restrict__ nmagL, float* __restrict__ nmagR){
  int idx = blockIdx.x*blockDim.x + threadIdx.x;
  if (idx >= BB*TT*323) return;
  int r = idx / 323, c = idx - r*323;
  const float* W; const float* bb; float* o; int oc, ow; bool sp=false;
  if (c < 32)      { W=WhL; bb=bhL; o=harmL; oc=c;     ow=32; }
  else if (c < 64) { W=WhR; bb=bhR; o=harmR; oc=c-32;  ow=32; }
  else if (c == 64){ W=Wam; bb=bam; o=amp;   oc=0;     ow=1; sp=true; }
  else if (c < 194){ W=WnL; bb=bnL; o=nmagL; oc=c-65;  ow=129; }
  else             { W=WnR; bb=bnR; o=nmagR; oc=c-194; ow=129; }
  const float* ip = post + r*MLPD;
  const float* wp = W + oc*MLPD;
  float acc = bb[oc];
  #pragma unroll 8
  for (int i=0;i<MLPD;i++) acc = fmaf(ip[i], wp[i], acc);
  float v;
  if (sp) v = fmaxf(acc, 0.0f) + log1pf(expf(-fabsf(acc)));   // softplus (stable)
  else    v = 1.0f/(1.0f+expf(-acc));                          // sigmoid
  o[r*ow + oc] = v;
}

// ---------------- numpy-exact pairwise mean of inst_freq per (b,k) ----------------
// numpy pairwise_sum_FLOAT on n=120000 forms a PERFECT depth-10 binary tree:
// 1024 leaves (n<=128) all at depth 10; combine == pairwise-adjacent tree.
__device__ float np_block_sum(const float* __restrict__ f0s, int off, int n, float kf){
  float r[8];
  #pragma unroll
  for (int j=0;j<8;j++) r[j] = __fmul_rn(f0_up_elem(f0s, off+j), kf);
  int lim = n - (n & 7);
  int i = 8;
  for (; i<lim; i+=8){
    #pragma unroll
    for (int j=0;j<8;j++)
      r[j] = __fadd_rn(r[j], __fmul_rn(f0_up_elem(f0s, off+i+j), kf));
  }
  float res = __fadd_rn(__fadd_rn(__fadd_rn(r[0],r[1]), __fadd_rn(r[2],r[3])),
                        __fadd_rn(__fadd_rn(r[4],r[5]), __fadd_rn(r[6],r[7])));
  for (; i<n; i++)
    res = __fadd_rn(res, __fmul_rn(f0_up_elem(f0s, off+i), kf));
  return res;
}

__global__ __launch_bounds__(256) void k_meanf0_np(const float* __restrict__ f0, float* __restrict__ ws){
  int b = blockIdx.x;
  int k = blockIdx.y;           // 0..31 -> harmonic k+1
  float kf = (float)(k+1);
  int tid = threadIdx.x;
  __shared__ float f0s[TT];
  __shared__ float red[256];
  for (int i=tid;i<TT;i+=256) f0s[i] = f0[b*TT+i];
  __syncthreads();
  // 4 adjacent leaves per thread; combine = depth-8 subtree ((l0+l1)+(l2+l3))
  float lv[4];
  #pragma unroll
  for (int q=0;q<4;q++){
    int leafIdx = tid*4 + q;
    int off = 0, n = NSAMP;
    #pragma unroll
    for (int lvl=9; lvl>=0; --lvl){
      int n2 = (n>>1); n2 -= (n2 & 7);
      if ((leafIdx >> lvl) & 1){ off += n2; n -= n2; } else { n = n2; }
    }
    lv[q] = np_block_sum(f0s, off, n, kf);
  }
  red[tid] = __fadd_rn(__fadd_rn(lv[0],lv[1]), __fadd_rn(lv[2],lv[3]));
  __syncthreads();
  // 8-level pairwise-adjacent LDS reduction (exact recursion order)
  for (int cnt=256; cnt>1; cnt>>=1){
    float v = 0.0f;
    int half = cnt>>1;
    if (tid < half) v = __fadd_rn(red[2*tid], red[2*tid+1]);
    __syncthreads();
    if (tid < half) red[tid] = v;
    __syncthreads();
  }
  if (tid==0){
    float mf = __fdiv_rn(red[0], 120000.0f);                  // np.mean: sum/n in f32
    float c1 = __fmul_rn((float)(2.0*M_PI/48000.0), mf);      // RN32(c32*mf32)
    ws[OFF_C1 + b*32 + k] = c1;
  }
}

// ---------------- forward STFT (windowed frames -> rfft bins) ----------------
__global__ __launch_bounds__(64) void k_stft(const float* __restrict__ nL, const float* __restrict__ nR,
                                             float* __restrict__ ws){
  int fr = blockIdx.x;           // b*NFRAMES + f
  int ch = blockIdx.y;
  int b = fr / NFRAMES, f = fr - b*NFRAMES;
  const float* x = (ch ? nR : nL) + (size_t)b*NSAMP;
  float* spec = ws + (ch ? OFF_SPECR : OFF_SPECL) + (size_t)fr*258;
  int j = threadIdx.x;
  __shared__ float frs[256];
  __shared__ float2 tw[256];
  for (int n=j;n<256;n+=64){
    double a = (2.0*M_PI/256.0)*(double)n;
    tw[n] = make_float2((float)cos(a), (float)sin(a));
    int xi = f*NHOPF + n - 128;
    xi = xi < 0 ? -xi : xi;
    xi = xi >= NSAMP ? 2*(NSAMP-1)-xi : xi;
    float w = (float)(0.5 - 0.5*cos(a));
    frs[n] = x[xi]*w;
  }
  __syncthreads();
  float re0=0.f, im0=0.f, re1=0.f, im1=0.f;
  int m0 = 0;                       // (j*n) & 255, incrementally
  #pragma unroll 4
  for (int n=0;n<256;n++){
    float fv = frs[n];
    int m1 = (m0 + ((n&3)<<6)) & 255;
    float2 t0 = tw[m0], t1 = tw[m1];
    re0 = fmaf(fv, t0.x, re0); im0 = fmaf(-fv, t0.y, im0);
    re1 = fmaf(fv, t1.x, re1); im1 = fmaf(-fv, t1.y, im1);
    m0 = (m0 + j) & 255;
  }
  // Nyquist bin 128: sum of (-1)^n * frs[n]; n = j + 64q -> sign = (-1)^j
  float p = frs[j] + frs[j+64] + frs[j+128] + frs[j+192];
  p = (j & 1) ? -p : p;
  for (int o=32;o>0;o>>=1) p += __shfl_down(p, o, 64);
  spec[2*j]   = re0; spec[2*j+1]   = im0;
  spec[2*(j+64)] = re1; spec[2*(j+64)+1] = im1;
  if (j==0){ spec[256] = p; spec[257] = 0.0f; }
}

// ---------------- mag filter + irfft + window ----------------
__global__ __launch_bounds__(256) void k_istft(float* __restrict__ ws){
  int fr = blockIdx.x;
  int ch = blockIdx.y;
  int b = fr / NFRAMES, f = fr - b*NFRAMES;
  const float* spec = ws + (ch ? OFF_SPECR : OFF_SPECL) + (size_t)fr*258;
  const float* nmag = ws + (ch ? OFF_NMAGR : OFF_NMAGL) + (size_t)b*TT*NBIN;
  float* outfr = ws + (ch ? OFF_FRR : OFF_FRL) + (size_t)fr*256;
  int t = threadIdx.x;
  __shared__ float2 tw[256];
  __shared__ float2 mx[NBIN];
  double a = (2.0*M_PI/256.0)*(double)t;
  float cz = (float)cos(a), sz = (float)sin(a);
  tw[t] = make_float2(cz, sz);
  if (t < NBIN){
    float pos = ((float)f + 0.5f) * R_MAG - 0.5f;
    pos = fminf(fmaxf(pos, 0.0f), 499.0f);
    int i0 = (int)pos, i1 = min(i0+1, TT-1);
    float w = pos - (float)i0;
    float mg = nmag[i0*NBIN + t]*(1.0f-w) + nmag[i1*NBIN + t]*w;
    mx[t] = make_float2(spec[2*t]*mg, spec[2*t+1]*mg);
  }
  __syncthreads();
  float acc0 = mx[0].x + ((t&1) ? -mx[128].x : mx[128].x);
  float acc = 0.0f;
  int mi = t;                      // (k*t)&255 for k=1
  #pragma unroll 4
  for (int k=1;k<128;k++){
    float2 v = mx[k];
    float2 tk = tw[mi];
    acc = fmaf(v.x, tk.x, acc);
    acc = fmaf(-v.y, tk.y, acc);
    mi = (mi + t) & 255;
  }
  float y = (acc0 + 2.0f*acc) * (1.0f/256.0f);
  float win = 0.5f - 0.5f*cz;
  outfr[t] = y*win;
}

// ---------------- final: harmonic synth + OLA gather ----------------
__global__ __launch_bounds__(256) void k_out(const float* __restrict__ f0,
    const float* __restrict__ ws, float* __restrict__ out){
  __shared__ float win2[256];
  __shared__ float c1s[BB*32];
  {
    int t = threadIdx.x;
    double a = (2.0*M_PI/256.0)*(double)t;
    float w = (float)(0.5 - 0.5*cos(a));
    win2[t] = w*w;
    if (t < BB*32) c1s[t] = ws[OFF_C1 + t];
  }
  __syncthreads();
  int idx = blockIdx.x*256 + threadIdx.x;
  if (idx >= BB*2*NSAMP) return;
  int m = idx % NSAMP;
  int bc = idx / NSAMP;
  int ch = bc & 1, b = bc >> 1;
  // f32 interp chain (bit-exact to numpy f32 elementwise)
  int i0,i1; float w,w1;
  up_coords(m,&i0,&i1,&w,&w1);
  const float* f0b = f0 + b*TT;
  float f0u = __fadd_rn(__fmul_rn(f0b[i0], w1), __fmul_rn(f0b[i1], w));
  const float* am = ws + OFF_AMP + b*TT;
  float oa = __fadd_rn(__fmul_rn(am[i0], w1), __fmul_rn(am[i1], w));
  const float* ha = ws + (ch ? OFF_HARMR : OFF_HARML) + (size_t)b*TT*NHARM;
  float tm = (float)m;
  float hsum = 0.0f;
  for (int k=1;k<=NHARM;k++){
    float instf = __fmul_rn(f0u, (float)k);          // RN32(f0_up*k), exact mask
    if (instf < 21600.0f){
      float a0 = ha[i0*NHARM + (k-1)], a1 = ha[i1*NHARM + (k-1)];
      float ak = __fadd_rn(__fmul_rn(a0, w1), __fmul_rn(a1, w));
      float ph = __fmul_rn(c1s[b*32 + (k-1)], tm);   // RN32(c1*t): exact f32 phase
      double rev = (double)ph * 0.15915494309189535; // /(2pi) in f64
      double fr2 = rev - floor(rev);
      float rad = (float)((fr2 - (fr2 >= 0.5 ? 1.0 : 0.0)) * 6.283185307179586);
      float s = sinf(rad);                            // sin(exact f32 phase)
      hsum = __fadd_rn(hsum, __fmul_rn(ak, s));
    }
  }
  float harm = __fmul_rn(hsum, oa);
  // noise OLA gather
  int p = m + 128;
  int fhi = min(p >> 6, NFRAMES-1);
  int flo = max((p - 192) >> 6, 0);
  const float* frb = ws + (ch ? OFF_FRR : OFF_FRL) + (size_t)b*NFRAMES*256;
  float nacc = 0.0f, wsum = 0.0f;
  for (int f=flo; f<=fhi; f++){
    int n = p - f*NHOPF;
    nacc += frb[f*256 + n];
    wsum += win2[n];
  }
  float noise = nacc / fmaxf(wsum, 1e-11f);
  out[idx] = __fadd_rn(harm, noise);
}

extern "C" void kernel_launch(void* const* d_in, const int* in_sizes, int n_in,
                              void* d_out, int out_size, void* d_ws, size_t ws_size,
                              hipStream_t stream){
  const float* f0  = (const float*)d_in[0];
  const float* ldb = (const float*)d_in[1];
  const float* vel = (const float*)d_in[2];
  const float* nL  = (const float*)d_in[3];
  const float* nR  = (const float*)d_in[4];
  const float* Wp1 = (const float*)d_in[5];
  const float* bp1 = (const float*)d_in[6];
  const float* Wp2 = (const float*)d_in[7];
  const float* bp2 = (const float*)d_in[8];
  const float* Wih = (const float*)d_in[9];
  const float* Whh = (const float*)d_in[10];
  const float* bih = (const float*)d_in[11];
  const float* bhh = (const float*)d_in[12];
  const float* Wpo = (const float*)d_in[13];
  const float* bpo = (const float*)d_in[14];
  const float* WhL = (const float*)d_in[15];
  const float* bhL = (const float*)d_in[16];
  const float* WhR = (const float*)d_in[17];
  const float* bhR = (const float*)d_in[18];
  const float* Wam = (const float*)d_in[19];
  const float* bam = (const float*)d_in[20];
  const float* WnL = (const float*)d_in[21];
  const float* bnL = (const float*)d_in[22];
  const float* WnR = (const float*)d_in[23];
  const float* bnR = (const float*)d_in[24];
  float* ws = (float*)d_ws;
  float* out = (float*)d_out;

  k_enc<<<(BB*TT+255)/256, 256, 0, stream>>>(f0, ldb, vel, ws+OFF_FEAT);
  k_mm<1><<<(BB*TT*128+255)/256, 256, 0, stream>>>(ws+OFF_FEAT, Wp1, bp1, ws+OFF_H1, BB*TT, 128, FEATD);
  k_mm<1><<<(BB*TT*128+255)/256, 256, 0, stream>>>(ws+OFF_H1, Wp2, bp2, ws+OFF_H2, BB*TT, 128, 128);
  k_mm<0><<<(BB*TT*192+255)/256, 256, 0, stream>>>(ws+OFF_H2, Wih, bih, ws+OFF_GI, BB*TT, 192, 128);
  k_gru<<<BB, 192, 0, stream>>>(ws+OFF_GI, Whh, bhh, ws+OFF_GOUT);
  k_mm<1><<<(BB*TT*128+255)/256, 256, 0, stream>>>(ws+OFF_GOUT, Wpo, bpo, ws+OFF_POST, BB*TT, 128, HID);
  k_heads<<<(BB*TT*323+255)/256, 256, 0, stream>>>(ws+OFF_POST, WhL,bhL, WhR,bhR, Wam,bam, WnL,bnL, WnR,bnR,
      ws+OFF_HARML, ws+OFF_HARMR, ws+OFF_AMP, ws+OFF_NMAGL, ws+OFF_NMAGR);
  dim3 gmf(BB, 32);
  k_meanf0_np<<<gmf, 256, 0, stream>>>(f0, ws);
  dim3 gs(BB*NFRAMES, 2);
  k_stft<<<gs, 64, 0, stream>>>(nL, nR, ws);
  k_istft<<<gs, 256, 0, stream>>>(ws);
  k_out<<<(BB*2*NSAMP+255)/256, 256, 0, stream>>>(f0, ws, out);
}

// Round 9
// 770.132 us; speedup vs baseline: 1.0043x; 1.0043x over previous
//
#include <hip/hip_runtime.h>
#include <math.h>

#ifndef M_PI
#define M_PI 3.14159265358979323846
#endif

#define BB 4
#define TT 500
#define NSAMP 120000
#define NHARM 32
#define NFFT 256
#define NBIN 129
#define NHOPF 64
#define NFRAMES 1876
#define HID 64
#define MLPD 128
#define FEATD 88

#define R_MAG ((float)(500.0/1876.0))
#define R_UP_F ((float)(500.0/120000.0))

// ---- workspace layout (float offsets) ----
#define OFF_HARML 0
#define OFF_HARMR 64000
#define OFF_AMP   128000
#define OFF_NMAGL 130000
#define OFF_NMAGR 388000
#define OFF_C1    646000            /* 128 floats: RN32(c32*mf32) per (b,k) */
#define OFF_TRUNK 646128
#define OFF_FEAT  (OFF_TRUNK)
#define OFF_H1    (OFF_FEAT+176000)
#define OFF_H2    (OFF_H1+256000)
#define OFF_GI    (OFF_H2+256000)
#define OFF_GOUT  (OFF_GI+384000)
#define OFF_POST  (OFF_GOUT+128000)
/* spec reuses trunk region (trunk dead after k_heads) */
#define OFF_SPECL (OFF_TRUNK)
#define OFF_SPECR (OFF_SPECL+1936032)
#define OFF_FRL   (OFF_SPECR+1936032)
#define OFF_FRR   (OFF_FRL+1921024)
/* total = 8360240 floats = 33.44 MB */

// f32 upsample position/interp chain, bit-exact to numpy float32 elementwise
__device__ __forceinline__ void up_coords(int m, int* i0, int* i1, float* w, float* w1){
  float pos = __fadd_rn(__fmul_rn(__fadd_rn((float)m, 0.5f), R_UP_F), -0.5f);
  pos = fminf(fmaxf(pos, 0.0f), 499.0f);
  int a = (int)pos;
  *i0 = a; *i1 = min(a+1, TT-1);
  float ww = __fsub_rn(pos, (float)a);
  *w = ww; *w1 = __fsub_rn(1.0f, ww);
}
__device__ __forceinline__ float f0_up_elem(const float* __restrict__ f0s, int m){
  int i0,i1; float w,w1;
  up_coords(m,&i0,&i1,&w,&w1);
  return __fadd_rn(__fmul_rn(f0s[i0], w1), __fmul_rn(f0s[i1], w));
}

// ---------------- encoding ----------------
__global__ void k_enc(const float* __restrict__ f0, const float* __restrict__ ldb,
                      const float* __restrict__ vel, float* __restrict__ feat){
  int idx = blockIdx.x*blockDim.x + threadIdx.x;
  if (idx >= BB*TT) return;
  int b = idx / TT;
  float f = f0[idx];
  float gate = (f > 0.0f) ? 1.0f : 0.0f;
  float fs = fmaxf(f, 20.0f);
  float fn = (logf(fs) - (float)2.995732273553991) / (float)5.5214609178622464;
  fn = fminf(fmaxf(fn, 0.0f), 1.0f);
  float ln = fminf(fmaxf((ldb[idx] + 80.0f) / 80.0f, 0.0f), 1.0f);
  float vn = fminf(fmaxf(vel[b] / 7.0f, 0.0f), 1.0f);
  float* o = feat + idx*FEATD;
  #pragma unroll 4
  for (int i=1;i<=32;i++){
    float ang = (float)M_PI * (float)i * fn;
    o[2*i-2] = sinf(ang)*gate;
    o[2*i-1] = cosf(ang)*gate;
  }
  #pragma unroll
  for (int i=1;i<=8;i++){
    float ang = (float)M_PI * (float)i * ln;
    o[64+2*i-2] = sinf(ang);
    o[64+2*i-1] = cosf(ang);
  }
  #pragma unroll
  for (int i=1;i<=4;i++){
    float ang = (float)M_PI * (float)i * vn;
    o[80+2*i-2] = sinf(ang);
    o[80+2*i-1] = cosf(ang);
  }
}

// ---------------- generic matmul: out = act(in @ W^T + b) ----------------
template<int ACT>
__global__ void k_mm(const float* __restrict__ in, const float* __restrict__ W,
                     const float* __restrict__ bias, float* __restrict__ out,
                     int R, int C, int IN){
  int idx = blockIdx.x*blockDim.x + threadIdx.x;
  if (idx >= R*C) return;
  int r = idx / C, c = idx - r*C;
  const float* ip = in + r*IN;
  const float* wp = W + c*IN;
  float acc = bias[c];
  #pragma unroll 8
  for (int i=0;i<IN;i++) acc = fmaf(ip[i], wp[i], acc);
  if (ACT==1) acc = fmaxf(acc, 0.0f);
  out[idx] = acc;
}

// ---------------- GRU recurrence (gi precomputed) ----------------
// 3 waves/block: wave g computes gate g's dot for all 64 outputs (lane j ->
// output j, 64 weights/lane). h[j] tracked redundantly per wave; h[i]
// broadcast via v_readlane. One barrier/step via dbuf ash.
// KEY FIX (rounds 5-8 post-mortem): the AMDGPU register allocator targets a
// default occupancy (~8 waves/EU -> 64-VGPR budget) and rematerializes
// loop-invariant weight loads from L2 every iteration instead of keeping
// them resident (VGPR_Count was 48-56 < the 64 weights needed). launch_bounds
// only sets the HARD budget, not the allocator's target. amdgpu_waves_per_eu
// (1,1) sets the target to 1 wave/EU (512-VGPR budget) -> weights stay live.
// Occupancy is irrelevant here: grid = 4 blocks x 3 waves on 256 CUs.
// Dot keeps the exact sequential i=0..63 fmaf chain -> bit-identical.
__global__
__attribute__((amdgpu_flat_work_group_size(192,192)))
__attribute__((amdgpu_waves_per_eu(1,1)))
void k_gru(const float* __restrict__ gi,
    const float* __restrict__ Whh, const float* __restrict__ bhh,
    float* __restrict__ gout){
  int b = blockIdx.x;
  int tid = threadIdx.x;        // 0..191
  int g = tid >> 6;             // gate index = wave index
  int j = tid & 63;
  float w[64];
  #pragma unroll
  for (int i=0;i<16;i++){
    float4 v = *(const float4*)(Whh + (size_t)(g*64+j)*64 + i*4);
    w[4*i]=v.x; w[4*i+1]=v.y; w[4*i+2]=v.z; w[4*i+3]=v.w;
  }
  __shared__ float ash[2][192];
  float br = bhh[j], bz = bhh[64+j], bn = bhh[128+j];
  const float* gp = gi + (size_t)b*TT*192 + j;
  float* op = gout + (size_t)b*TT*64 + j;
  float hreg = 0.0f;            // h[j], redundant on all 3 waves
  float gr = gp[0], gz = gp[64], gn = gp[128];
  for (int t=0;t<TT;t++){
    // prefetch next step's gate inputs (latency hides under the dot)
    int tn = min(t+1, TT-1);
    float gr2 = gp[tn*192], gz2 = gp[tn*192+64], gn2 = gp[tn*192+128];
    // dot(w, h): h[i] broadcast by readlane; exact sequential i=0..63 chain
    float acc = 0.f;
    #pragma unroll
    for (int i=0;i<64;i++){
      float hi = __uint_as_float(__builtin_amdgcn_readlane(__float_as_uint(hreg), i));
      acc = fmaf(w[i], hi, acc);
    }
    ash[t&1][tid] = acc;
    __syncthreads();            // single barrier per step (dbuf makes it safe)
    float ar = ash[t&1][j], az = ash[t&1][64+j], an = ash[t&1][128+j];
    float r = 1.0f/(1.0f+expf(-(gr+ar+br)));
    float z = 1.0f/(1.0f+expf(-(gz+az+bz)));
    float n = tanhf(gn + r*(an+bn));
    hreg = (1.0f - z)*n + z*hreg;
    if (g==0) op[t*64] = hreg;
    gr=gr2; gz=gz2; gn=gn2;
  }
}

// ---------------- heads ----------------
__global__ void k_heads(const float* __restrict__ post,
  const float* __restrict__ WhL, const float* __restrict__ bhL,
  const float* __restrict__ WhR, const float* __restrict__ bhR,
  const float* __restrict__ Wam, const float* __restrict__ bam,
  const float* __restrict__ WnL, const float* __restrict__ bnL,
  const float* __restrict__ WnR, const float* __restrict__ bnR,
  float* __restrict__ harmL, float* __restrict__ harmR, float* __restrict__ amp,
  float* __restrict__ nmagL, float* __restrict__ nmagR){
  int idx = blockIdx.x*blockDim.x + threadIdx.x;
  if (idx >= BB*TT*323) return;
  int r = idx / 323, c = idx - r*323;
  const float* W; const float* bb; float* o; int oc, ow; bool sp=false;
  if (c < 32)      { W=WhL; bb=bhL; o=harmL; oc=c;     ow=32; }
  else if (c < 64) { W=WhR; bb=bhR; o=harmR; oc=c-32;  ow=32; }
  else if (c == 64){ W=Wam; bb=bam; o=amp;   oc=0;     ow=1; sp=true; }
  else if (c < 194){ W=WnL; bb=bnL; o=nmagL; oc=c-65;  ow=129; }
  else             { W=WnR; bb=bnR; o=nmagR; oc=c-194; ow=129; }
  const float* ip = post + r*MLPD;
  const float* wp = W + oc*MLPD;
  float acc = bb[oc];
  #pragma unroll 8
  for (int i=0;i<MLPD;i++) acc = fmaf(ip[i], wp[i], acc);
  float v;
  if (sp) v = fmaxf(acc, 0.0f) + log1pf(expf(-fabsf(acc)));   // softplus (stable)
  else    v = 1.0f/(1.0f+expf(-acc));                          // sigmoid
  o[r*ow + oc] = v;
}

// ---------------- numpy-exact pairwise mean of inst_freq per (b,k) ----------------
// numpy pairwise_sum_FLOAT on n=120000 forms a PERFECT depth-10 binary tree:
// 1024 leaves (n<=128) all at depth 10; combine == pairwise-adjacent tree.
__device__ float np_block_sum(const float* __restrict__ f0s, int off, int n, float kf){
  float r[8];
  #pragma unroll
  for (int j=0;j<8;j++) r[j] = __fmul_rn(f0_up_elem(f0s, off+j), kf);
  int lim = n - (n & 7);
  int i = 8;
  for (; i<lim; i+=8){
    #pragma unroll
    for (int j=0;j<8;j++)
      r[j] = __fadd_rn(r[j], __fmul_rn(f0_up_elem(f0s, off+i+j), kf));
  }
  float res = __fadd_rn(__fadd_rn(__fadd_rn(r[0],r[1]), __fadd_rn(r[2],r[3])),
                        __fadd_rn(__fadd_rn(r[4],r[5]), __fadd_rn(r[6],r[7])));
  for (; i<n; i++)
    res = __fadd_rn(res, __fmul_rn(f0_up_elem(f0s, off+i), kf));
  return res;
}

__global__ __launch_bounds__(256) void k_meanf0_np(const float* __restrict__ f0, float* __restrict__ ws){
  int b = blockIdx.x;
  int k = blockIdx.y;           // 0..31 -> harmonic k+1
  float kf = (float)(k+1);
  int tid = threadIdx.x;
  __shared__ float f0s[TT];
  __shared__ float red[256];
  for (int i=tid;i<TT;i+=256) f0s[i] = f0[b*TT+i];
  __syncthreads();
  // 4 adjacent leaves per thread; combine = depth-8 subtree ((l0+l1)+(l2+l3))
  float lv[4];
  #pragma unroll
  for (int q=0;q<4;q++){
    int leafIdx = tid*4 + q;
    int off = 0, n = NSAMP;
    #pragma unroll
    for (int lvl=9; lvl>=0; --lvl){
      int n2 = (n>>1); n2 -= (n2 & 7);
      if ((leafIdx >> lvl) & 1){ off += n2; n -= n2; } else { n = n2; }
    }
    lv[q] = np_block_sum(f0s, off, n, kf);
  }
  red[tid] = __fadd_rn(__fadd_rn(lv[0],lv[1]), __fadd_rn(lv[2],lv[3]));
  __syncthreads();
  // 8-level pairwise-adjacent LDS reduction (exact recursion order)
  for (int cnt=256; cnt>1; cnt>>=1){
    float v = 0.0f;
    int half = cnt>>1;
    if (tid < half) v = __fadd_rn(red[2*tid], red[2*tid+1]);
    __syncthreads();
    if (tid < half) red[tid] = v;
    __syncthreads();
  }
  if (tid==0){
    float mf = __fdiv_rn(red[0], 120000.0f);                  // np.mean: sum/n in f32
    float c1 = __fmul_rn((float)(2.0*M_PI/48000.0), mf);      // RN32(c32*mf32)
    ws[OFF_C1 + b*32 + k] = c1;
  }
}

// ---------------- forward STFT (windowed frames -> rfft bins) ----------------
__global__ __launch_bounds__(64) void k_stft(const float* __restrict__ nL, const float* __restrict__ nR,
                                             float* __restrict__ ws){
  int fr = blockIdx.x;           // b*NFRAMES + f
  int ch = blockIdx.y;
  int b = fr / NFRAMES, f = fr - b*NFRAMES;
  const float* x = (ch ? nR : nL) + (size_t)b*NSAMP;
  float* spec = ws + (ch ? OFF_SPECR : OFF_SPECL) + (size_t)fr*258;
  int j = threadIdx.x;
  __shared__ float frs[256];
  __shared__ float2 tw[256];
  for (int n=j;n<256;n+=64){
    double a = (2.0*M_PI/256.0)*(double)n;
    tw[n] = make_float2((float)cos(a), (float)sin(a));
    int xi = f*NHOPF + n - 128;
    xi = xi < 0 ? -xi : xi;
    xi = xi >= NSAMP ? 2*(NSAMP-1)-xi : xi;
    float w = (float)(0.5 - 0.5*cos(a));
    frs[n] = x[xi]*w;
  }
  __syncthreads();
  float re0=0.f, im0=0.f, re1=0.f, im1=0.f;
  int m0 = 0;                       // (j*n) & 255, incrementally
  #pragma unroll 4
  for (int n=0;n<256;n++){
    float fv = frs[n];
    int m1 = (m0 + ((n&3)<<6)) & 255;
    float2 t0 = tw[m0], t1 = tw[m1];
    re0 = fmaf(fv, t0.x, re0); im0 = fmaf(-fv, t0.y, im0);
    re1 = fmaf(fv, t1.x, re1); im1 = fmaf(-fv, t1.y, im1);
    m0 = (m0 + j) & 255;
  }
  // Nyquist bin 128: sum of (-1)^n * frs[n]; n = j + 64q -> sign = (-1)^j
  float p = frs[j] + frs[j+64] + frs[j+128] + frs[j+192];
  p = (j & 1) ? -p : p;
  for (int o=32;o>0;o>>=1) p += __shfl_down(p, o, 64);
  spec[2*j]   = re0; spec[2*j+1]   = im0;
  spec[2*(j+64)] = re1; spec[2*(j+64)+1] = im1;
  if (j==0){ spec[256] = p; spec[257] = 0.0f; }
}

// ---------------- mag filter + irfft + window ----------------
__global__ __launch_bounds__(256) void k_istft(float* __restrict__ ws){
  int fr = blockIdx.x;
  int ch = blockIdx.y;
  int b = fr / NFRAMES, f = fr - b*NFRAMES;
  const float* spec = ws + (ch ? OFF_SPECR : OFF_SPECL) + (size_t)fr*258;
  const float* nmag = ws + (ch ? OFF_NMAGR : OFF_NMAGL) + (size_t)b*TT*NBIN;
  float* outfr = ws + (ch ? OFF_FRR : OFF_FRL) + (size_t)fr*256;
  int t = threadIdx.x;
  __shared__ float2 tw[256];
  __shared__ float2 mx[NBIN];
  double a = (2.0*M_PI/256.0)*(double)t;
  float cz = (float)cos(a), sz = (float)sin(a);
  tw[t] = make_float2(cz, sz);
  if (t < NBIN){
    float pos = ((float)f + 0.5f) * R_MAG - 0.5f;
    pos = fminf(fmaxf(pos, 0.0f), 499.0f);
    int i0 = (int)pos, i1 = min(i0+1, TT-1);
    float w = pos - (float)i0;
    float mg = nmag[i0*NBIN + t]*(1.0f-w) + nmag[i1*NBIN + t]*w;
    mx[t] = make_float2(spec[2*t]*mg, spec[2*t+1]*mg);
  }
  __syncthreads();
  float acc0 = mx[0].x + ((t&1) ? -mx[128].x : mx[128].x);
  float acc = 0.0f;
  int mi = t;                      // (k*t)&255 for k=1
  #pragma unroll 4
  for (int k=1;k<128;k++){
    float2 v = mx[k];
    float2 tk = tw[mi];
    acc = fmaf(v.x, tk.x, acc);
    acc = fmaf(-v.y, tk.y, acc);
    mi = (mi + t) & 255;
  }
  float y = (acc0 + 2.0f*acc) * (1.0f/256.0f);
  float win = 0.5f - 0.5f*cz;
  outfr[t] = y*win;
}

// ---------------- final: harmonic synth + OLA gather ----------------
__global__ __launch_bounds__(256) void k_out(const float* __restrict__ f0,
    const float* __restrict__ ws, float* __restrict__ out){
  __shared__ float win2[256];
  __shared__ float c1s[BB*32];
  {
    int t = threadIdx.x;
    double a = (2.0*M_PI/256.0)*(double)t;
    float w = (float)(0.5 - 0.5*cos(a));
    win2[t] = w*w;
    if (t < BB*32) c1s[t] = ws[OFF_C1 + t];
  }
  __syncthreads();
  int idx = blockIdx.x*256 + threadIdx.x;
  if (idx >= BB*2*NSAMP) return;
  int m = idx % NSAMP;
  int bc = idx / NSAMP;
  int ch = bc & 1, b = bc >> 1;
  // f32 interp chain (bit-exact to numpy f32 elementwise)
  int i0,i1; float w,w1;
  up_coords(m,&i0,&i1,&w,&w1);
  const float* f0b = f0 + b*TT;
  float f0u = __fadd_rn(__fmul_rn(f0b[i0], w1), __fmul_rn(f0b[i1], w));
  const float* am = ws + OFF_AMP + b*TT;
  float oa = __fadd_rn(__fmul_rn(am[i0], w1), __fmul_rn(am[i1], w));
  const float* ha = ws + (ch ? OFF_HARMR : OFF_HARML) + (size_t)b*TT*NHARM;
  float tm = (float)m;
  float hsum = 0.0f;
  for (int k=1;k<=NHARM;k++){
    float instf = __fmul_rn(f0u, (float)k);          // RN32(f0_up*k), exact mask
    if (instf < 21600.0f){
      float a0 = ha[i0*NHARM + (k-1)], a1 = ha[i1*NHARM + (k-1)];
      float ak = __fadd_rn(__fmul_rn(a0, w1), __fmul_rn(a1, w));
      float ph = __fmul_rn(c1s[b*32 + (k-1)], tm);   // RN32(c1*t): exact f32 phase
      double rev = (double)ph * 0.15915494309189535; // /(2pi) in f64
      double fr2 = rev - floor(rev);
      float rad = (float)((fr2 - (fr2 >= 0.5 ? 1.0 : 0.0)) * 6.283185307179586);
      float s = sinf(rad);                            // sin(exact f32 phase)
      hsum = __fadd_rn(hsum, __fmul_rn(ak, s));
    }
  }
  float harm = __fmul_rn(hsum, oa);
  // noise OLA gather
  int p = m + 128;
  int fhi = min(p >> 6, NFRAMES-1);
  int flo = max((p - 192) >> 6, 0);
  const float* frb = ws + (ch ? OFF_FRR : OFF_FRL) + (size_t)b*NFRAMES*256;
  float nacc = 0.0f, wsum = 0.0f;
  for (int f=flo; f<=fhi; f++){
    int n = p - f*NHOPF;
    nacc += frb[f*256 + n];
    wsum += win2[n];
  }
  float noise = nacc / fmaxf(wsum, 1e-11f);
  out[idx] = __fadd_rn(harm, noise);
}

extern "C" void kernel_launch(void* const* d_in, const int* in_sizes, int n_in,
                              void* d_out, int out_size, void* d_ws, size_t ws_size,
                              hipStream_t stream){
  const float* f0  = (const float*)d_in[0];
  const float* ldb = (const float*)d_in[1];
  const float* vel = (const float*)d_in[2];
  const float* nL  = (const float*)d_in[3];
  const float* nR  = (const float*)d_in[4];
  const float* Wp1 = (const float*)d_in[5];
  const float* bp1 = (const float*)d_in[6];
  const float* Wp2 = (const float*)d_in[7];
  const float* bp2 = (const float*)d_in[8];
  const float* Wih = (const float*)d_in[9];
  const float* Whh = (const float*)d_in[10];
  const float* bih = (const float*)d_in[11];
  const float* bhh = (const float*)d_in[12];
  const float* Wpo = (const float*)d_in[13];
  const float* bpo = (const float*)d_in[14];
  const float* WhL = (const float*)d_in[15];
  const float* bhL = (const float*)d_in[16];
  const float* WhR = (const float*)d_in[17];
  const float* bhR = (const float*)d_in[18];
  const float* Wam = (const float*)d_in[19];
  const float* bam = (const float*)d_in[20];
  const float* WnL = (const float*)d_in[21];
  const float* bnL = (const float*)d_in[22];
  const float* WnR = (const float*)d_in[23];
  const float* bnR = (const float*)d_in[24];
  float* ws = (float*)d_ws;
  float* out = (float*)d_out;

  k_enc<<<(BB*TT+255)/256, 256, 0, stream>>>(f0, ldb, vel, ws+OFF_FEAT);
  k_mm<1><<<(BB*TT*128+255)/256, 256, 0, stream>>>(ws+OFF_FEAT, Wp1, bp1, ws+OFF_H1, BB*TT, 128, FEATD);
  k_mm<1><<<(BB*TT*128+255)/256, 256, 0, stream>>>(ws+OFF_H1, Wp2, bp2, ws+OFF_H2, BB*TT, 128, 128);
  k_mm<0><<<(BB*TT*192+255)/256, 256, 0, stream>>>(ws+OFF_H2, Wih, bih, ws+OFF_GI, BB*TT, 192, 128);
  k_gru<<<BB, 192, 0, stream>>>(ws+OFF_GI, Whh, bhh, ws+OFF_GOUT);
  k_mm<1><<<(BB*TT*128+255)/256, 256, 0, stream>>>(ws+OFF_GOUT, Wpo, bpo, ws+OFF_POST, BB*TT, 128, HID);
  k_heads<<<(BB*TT*323+255)/256, 256, 0, stream>>>(ws+OFF_POST, WhL,bhL, WhR,bhR, Wam,bam, WnL,bnL, WnR,bnR,
      ws+OFF_HARML, ws+OFF_HARMR, ws+OFF_AMP, ws+OFF_NMAGL, ws+OFF_NMAGR);
  dim3 gmf(BB, 32);
  k_meanf0_np<<<gmf, 256, 0, stream>>>(f0, ws);
  dim3 gs(BB*NFRAMES, 2);
  k_stft<<<gs, 64, 0, stream>>>(nL, nR, ws);
  k_istft<<<gs, 256, 0, stream>>>(ws);
  k_out<<<(BB*2*NSAMP+255)/256, 256, 0, stream>>>(f0, ws, out);
}

// Round 10
// 704.903 us; speedup vs baseline: 1.0972x; 1.0925x over previous
//
#include <hip/hip_runtime.h>
#include <math.h>

#ifndef M_PI
#define M_PI 3.14159265358979323846
#endif

#define BB 4
#define TT 500
#define NSAMP 120000
#define NHARM 32
#define NFFT 256
#define NBIN 129
#define NHOPF 64
#define NFRAMES 1876
#define HID 64
#define MLPD 128
#define FEATD 88

#define R_MAG ((float)(500.0/1876.0))
#define R_UP_F ((float)(500.0/120000.0))

// ---- workspace layout (float offsets) ----
#define OFF_HARML 0
#define OFF_HARMR 64000
#define OFF_AMP   128000
#define OFF_NMAGL 130000
#define OFF_NMAGR 388000
#define OFF_C1    646000            /* 128 floats: RN32(c32*mf32) per (b,k) */
#define OFF_TRUNK 646128
#define OFF_FEAT  (OFF_TRUNK)
#define OFF_H1    (OFF_FEAT+176000)
#define OFF_H2    (OFF_H1+256000)
#define OFF_GI    (OFF_H2+256000)
#define OFF_GOUT  (OFF_GI+384000)
#define OFF_POST  (OFF_GOUT+128000)
/* spec reuses trunk region (trunk dead after k_heads) */
#define OFF_SPECL (OFF_TRUNK)
#define OFF_SPECR (OFF_SPECL+1936032)
#define OFF_FRL   (OFF_SPECR+1936032)
#define OFF_FRR   (OFF_FRL+1921024)
/* total = 8360240 floats = 33.44 MB */

// f32 upsample position/interp chain, bit-exact to numpy float32 elementwise
__device__ __forceinline__ void up_coords(int m, int* i0, int* i1, float* w, float* w1){
  float pos = __fadd_rn(__fmul_rn(__fadd_rn((float)m, 0.5f), R_UP_F), -0.5f);
  pos = fminf(fmaxf(pos, 0.0f), 499.0f);
  int a = (int)pos;
  *i0 = a; *i1 = min(a+1, TT-1);
  float ww = __fsub_rn(pos, (float)a);
  *w = ww; *w1 = __fsub_rn(1.0f, ww);
}
__device__ __forceinline__ float f0_up_elem(const float* __restrict__ f0s, int m){
  int i0,i1; float w,w1;
  up_coords(m,&i0,&i1,&w,&w1);
  return __fadd_rn(__fmul_rn(f0s[i0], w1), __fmul_rn(f0s[i1], w));
}

// ---------------- encoding ----------------
__global__ void k_enc(const float* __restrict__ f0, const float* __restrict__ ldb,
                      const float* __restrict__ vel, float* __restrict__ feat){
  int idx = blockIdx.x*blockDim.x + threadIdx.x;
  if (idx >= BB*TT) return;
  int b = idx / TT;
  float f = f0[idx];
  float gate = (f > 0.0f) ? 1.0f : 0.0f;
  float fs = fmaxf(f, 20.0f);
  float fn = (logf(fs) - (float)2.995732273553991) / (float)5.5214609178622464;
  fn = fminf(fmaxf(fn, 0.0f), 1.0f);
  float ln = fminf(fmaxf((ldb[idx] + 80.0f) / 80.0f, 0.0f), 1.0f);
  float vn = fminf(fmaxf(vel[b] / 7.0f, 0.0f), 1.0f);
  float* o = feat + idx*FEATD;
  #pragma unroll 4
  for (int i=1;i<=32;i++){
    float ang = (float)M_PI * (float)i * fn;
    o[2*i-2] = sinf(ang)*gate;
    o[2*i-1] = cosf(ang)*gate;
  }
  #pragma unroll
  for (int i=1;i<=8;i++){
    float ang = (float)M_PI * (float)i * ln;
    o[64+2*i-2] = sinf(ang);
    o[64+2*i-1] = cosf(ang);
  }
  #pragma unroll
  for (int i=1;i<=4;i++){
    float ang = (float)M_PI * (float)i * vn;
    o[80+2*i-2] = sinf(ang);
    o[80+2*i-1] = cosf(ang);
  }
}

// ---------------- generic matmul: out = act(in @ W^T + b) ----------------
template<int ACT>
__global__ void k_mm(const float* __restrict__ in, const float* __restrict__ W,
                     const float* __restrict__ bias, float* __restrict__ out,
                     int R, int C, int IN){
  int idx = blockIdx.x*blockDim.x + threadIdx.x;
  if (idx >= R*C) return;
  int r = idx / C, c = idx - r*C;
  const float* ip = in + r*IN;
  const float* wp = W + c*IN;
  float acc = bias[c];
  #pragma unroll 8
  for (int i=0;i<IN;i++) acc = fmaf(ip[i], wp[i], acc);
  if (ACT==1) acc = fmaxf(acc, 0.0f);
  out[idx] = acc;
}

// ---------------- GRU recurrence (gi precomputed) ----------------
// SINGLE WAVE per batch, ZERO barriers. Post-mortem r9: weight residency
// (VGPR 132) did NOT speed up the 3-wave version -> the cost was the
// per-iteration __syncthreads barrier drain (s_waitcnt vmcnt(0) before
// s_barrier) exposing gi's HBM latency (~900 cyc) every step, plus the
// slower readlane dot. Fix: no barriers at all -> depth-2 register
// prefetch of gi stays in flight across iterations (6 outstanding loads,
// compiler emits counted vmcnt). 192 weights/lane stay resident thanks to
// amdgpu_waves_per_eu(1,1) (validated r9: raises allocator budget; r5's
// launch_bounds alone did not). Dot = exact same i=0..63 fmaf chains
// as all passing rounds -> bit-identical trajectory.
__global__
__attribute__((amdgpu_flat_work_group_size(64,64)))
__attribute__((amdgpu_waves_per_eu(1,1)))
void k_gru(const float* __restrict__ gi,
    const float* __restrict__ Whh, const float* __restrict__ bhh,
    float* __restrict__ gout){
  int b = blockIdx.x;
  int j = threadIdx.x;
  float wr[64], wz[64], wn[64];
  #pragma unroll
  for (int i=0;i<16;i++){
    float4 a = *(const float4*)(Whh + (j)*64     + i*4);
    float4 c = *(const float4*)(Whh + (64+j)*64  + i*4);
    float4 d = *(const float4*)(Whh + (128+j)*64 + i*4);
    wr[4*i]=a.x; wr[4*i+1]=a.y; wr[4*i+2]=a.z; wr[4*i+3]=a.w;
    wz[4*i]=c.x; wz[4*i+1]=c.y; wz[4*i+2]=c.z; wz[4*i+3]=c.w;
    wn[4*i]=d.x; wn[4*i+1]=d.y; wn[4*i+2]=d.z; wn[4*i+3]=d.w;
  }
  float br = bhh[j], bz = bhh[64+j], bn = bhh[128+j];
  const float* gp = gi + (size_t)b*TT*192 + j;
  float* op = gout + (size_t)b*TT*64 + j;
  float hreg = 0.0f;
  // depth-2 prefetch: loads for t and t+1 in flight before the loop
  float gr0 = gp[0],   gz0 = gp[64],     gn0 = gp[128];
  float gr1 = gp[192], gz1 = gp[192+64], gn1 = gp[192+128];
  for (int t=0;t<TT;t++){
    int tn = min(t+2, TT-1);
    float gr2 = gp[tn*192], gz2 = gp[tn*192+64], gn2 = gp[tn*192+128];
    // dot(w,h): h[i] broadcast via readlane; 3 independent fmaf chains,
    // each in the exact sequential i=0..63 order (bit-identical)
    float ar=0.f, az=0.f, an=0.f;
    #pragma unroll
    for (int i=0;i<64;i++){
      float hi = __uint_as_float(__builtin_amdgcn_readlane(__float_as_uint(hreg), i));
      ar = fmaf(wr[i], hi, ar);
      az = fmaf(wz[i], hi, az);
      an = fmaf(wn[i], hi, an);
    }
    float r = 1.0f/(1.0f+expf(-(gr0+ar+br)));
    float z = 1.0f/(1.0f+expf(-(gz0+az+bz)));
    float n = tanhf(gn0 + r*(an+bn));
    hreg = (1.0f - z)*n + z*hreg;
    op[t*64] = hreg;
    gr0=gr1; gz0=gz1; gn0=gn1;
    gr1=gr2; gz1=gz2; gn1=gn2;
  }
}

// ---------------- heads ----------------
__global__ void k_heads(const float* __restrict__ post,
  const float* __restrict__ WhL, const float* __restrict__ bhL,
  const float* __restrict__ WhR, const float* __restrict__ bhR,
  const float* __restrict__ Wam, const float* __restrict__ bam,
  const float* __restrict__ WnL, const float* __restrict__ bnL,
  const float* __restrict__ WnR, const float* __restrict__ bnR,
  float* __restrict__ harmL, float* __restrict__ harmR, float* __restrict__ amp,
  float* __restrict__ nmagL, float* __restrict__ nmagR){
  int idx = blockIdx.x*blockDim.x + threadIdx.x;
  if (idx >= BB*TT*323) return;
  int r = idx / 323, c = idx - r*323;
  const float* W; const float* bb; float* o; int oc, ow; bool sp=false;
  if (c < 32)      { W=WhL; bb=bhL; o=harmL; oc=c;     ow=32; }
  else if (c < 64) { W=WhR; bb=bhR; o=harmR; oc=c-32;  ow=32; }
  else if (c == 64){ W=Wam; bb=bam; o=amp;   oc=0;     ow=1; sp=true; }
  else if (c < 194){ W=WnL; bb=bnL; o=nmagL; oc=c-65;  ow=129; }
  else             { W=WnR; bb=bnR; o=nmagR; oc=c-194; ow=129; }
  const float* ip = post + r*MLPD;
  const float* wp = W + oc*MLPD;
  float acc = bb[oc];
  #pragma unroll 8
  for (int i=0;i<MLPD;i++) acc = fmaf(ip[i], wp[i], acc);
  float v;
  if (sp) v = fmaxf(acc, 0.0f) + log1pf(expf(-fabsf(acc)));   // softplus (stable)
  else    v = 1.0f/(1.0f+expf(-acc));                          // sigmoid
  o[r*ow + oc] = v;
}

// ---------------- numpy-exact pairwise mean of inst_freq per (b,k) ----------------
// numpy pairwise_sum_FLOAT on n=120000 forms a PERFECT depth-10 binary tree:
// 1024 leaves (n<=128) all at depth 10; combine == pairwise-adjacent tree.
__device__ float np_block_sum(const float* __restrict__ f0s, int off, int n, float kf){
  float r[8];
  #pragma unroll
  for (int j=0;j<8;j++) r[j] = __fmul_rn(f0_up_elem(f0s, off+j), kf);
  int lim = n - (n & 7);
  int i = 8;
  for (; i<lim; i+=8){
    #pragma unroll
    for (int j=0;j<8;j++)
      r[j] = __fadd_rn(r[j], __fmul_rn(f0_up_elem(f0s, off+i+j), kf));
  }
  float res = __fadd_rn(__fadd_rn(__fadd_rn(r[0],r[1]), __fadd_rn(r[2],r[3])),
                        __fadd_rn(__fadd_rn(r[4],r[5]), __fadd_rn(r[6],r[7])));
  for (; i<n; i++)
    res = __fadd_rn(res, __fmul_rn(f0_up_elem(f0s, off+i), kf));
  return res;
}

__global__ __launch_bounds__(256) void k_meanf0_np(const float* __restrict__ f0, float* __restrict__ ws){
  int b = blockIdx.x;
  int k = blockIdx.y;           // 0..31 -> harmonic k+1
  float kf = (float)(k+1);
  int tid = threadIdx.x;
  __shared__ float f0s[TT];
  __shared__ float red[256];
  for (int i=tid;i<TT;i+=256) f0s[i] = f0[b*TT+i];
  __syncthreads();
  // 4 adjacent leaves per thread; combine = depth-8 subtree ((l0+l1)+(l2+l3))
  float lv[4];
  #pragma unroll
  for (int q=0;q<4;q++){
    int leafIdx = tid*4 + q;
    int off = 0, n = NSAMP;
    #pragma unroll
    for (int lvl=9; lvl>=0; --lvl){
      int n2 = (n>>1); n2 -= (n2 & 7);
      if ((leafIdx >> lvl) & 1){ off += n2; n -= n2; } else { n = n2; }
    }
    lv[q] = np_block_sum(f0s, off, n, kf);
  }
  red[tid] = __fadd_rn(__fadd_rn(lv[0],lv[1]), __fadd_rn(lv[2],lv[3]));
  __syncthreads();
  // 8-level pairwise-adjacent LDS reduction (exact recursion order)
  for (int cnt=256; cnt>1; cnt>>=1){
    float v = 0.0f;
    int half = cnt>>1;
    if (tid < half) v = __fadd_rn(red[2*tid], red[2*tid+1]);
    __syncthreads();
    if (tid < half) red[tid] = v;
    __syncthreads();
  }
  if (tid==0){
    float mf = __fdiv_rn(red[0], 120000.0f);                  // np.mean: sum/n in f32
    float c1 = __fmul_rn((float)(2.0*M_PI/48000.0), mf);      // RN32(c32*mf32)
    ws[OFF_C1 + b*32 + k] = c1;
  }
}

// ---------------- forward STFT (windowed frames -> rfft bins) ----------------
__global__ __launch_bounds__(64) void k_stft(const float* __restrict__ nL, const float* __restrict__ nR,
                                             float* __restrict__ ws){
  int fr = blockIdx.x;           // b*NFRAMES + f
  int ch = blockIdx.y;
  int b = fr / NFRAMES, f = fr - b*NFRAMES;
  const float* x = (ch ? nR : nL) + (size_t)b*NSAMP;
  float* spec = ws + (ch ? OFF_SPECR : OFF_SPECL) + (size_t)fr*258;
  int j = threadIdx.x;
  __shared__ float frs[256];
  __shared__ float2 tw[256];
  for (int n=j;n<256;n+=64){
    double a = (2.0*M_PI/256.0)*(double)n;
    tw[n] = make_float2((float)cos(a), (float)sin(a));
    int xi = f*NHOPF + n - 128;
    xi = xi < 0 ? -xi : xi;
    xi = xi >= NSAMP ? 2*(NSAMP-1)-xi : xi;
    float w = (float)(0.5 - 0.5*cos(a));
    frs[n] = x[xi]*w;
  }
  __syncthreads();
  float re0=0.f, im0=0.f, re1=0.f, im1=0.f;
  int m0 = 0;                       // (j*n) & 255, incrementally
  #pragma unroll 4
  for (int n=0;n<256;n++){
    float fv = frs[n];
    int m1 = (m0 + ((n&3)<<6)) & 255;
    float2 t0 = tw[m0], t1 = tw[m1];
    re0 = fmaf(fv, t0.x, re0); im0 = fmaf(-fv, t0.y, im0);
    re1 = fmaf(fv, t1.x, re1); im1 = fmaf(-fv, t1.y, im1);
    m0 = (m0 + j) & 255;
  }
  // Nyquist bin 128: sum of (-1)^n * frs[n]; n = j + 64q -> sign = (-1)^j
  float p = frs[j] + frs[j+64] + frs[j+128] + frs[j+192];
  p = (j & 1) ? -p : p;
  for (int o=32;o>0;o>>=1) p += __shfl_down(p, o, 64);
  spec[2*j]   = re0; spec[2*j+1]   = im0;
  spec[2*(j+64)] = re1; spec[2*(j+64)+1] = im1;
  if (j==0){ spec[256] = p; spec[257] = 0.0f; }
}

// ---------------- mag filter + irfft + window ----------------
__global__ __launch_bounds__(256) void k_istft(float* __restrict__ ws){
  int fr = blockIdx.x;
  int ch = blockIdx.y;
  int b = fr / NFRAMES, f = fr - b*NFRAMES;
  const float* spec = ws + (ch ? OFF_SPECR : OFF_SPECL) + (size_t)fr*258;
  const float* nmag = ws + (ch ? OFF_NMAGR : OFF_NMAGL) + (size_t)b*TT*NBIN;
  float* outfr = ws + (ch ? OFF_FRR : OFF_FRL) + (size_t)fr*256;
  int t = threadIdx.x;
  __shared__ float2 tw[256];
  __shared__ float2 mx[NBIN];
  double a = (2.0*M_PI/256.0)*(double)t;
  float cz = (float)cos(a), sz = (float)sin(a);
  tw[t] = make_float2(cz, sz);
  if (t < NBIN){
    float pos = ((float)f + 0.5f) * R_MAG - 0.5f;
    pos = fminf(fmaxf(pos, 0.0f), 499.0f);
    int i0 = (int)pos, i1 = min(i0+1, TT-1);
    float w = pos - (float)i0;
    float mg = nmag[i0*NBIN + t]*(1.0f-w) + nmag[i1*NBIN + t]*w;
    mx[t] = make_float2(spec[2*t]*mg, spec[2*t+1]*mg);
  }
  __syncthreads();
  float acc0 = mx[0].x + ((t&1) ? -mx[128].x : mx[128].x);
  float acc = 0.0f;
  int mi = t;                      // (k*t)&255 for k=1
  #pragma unroll 4
  for (int k=1;k<128;k++){
    float2 v = mx[k];
    float2 tk = tw[mi];
    acc = fmaf(v.x, tk.x, acc);
    acc = fmaf(-v.y, tk.y, acc);
    mi = (mi + t) & 255;
  }
  float y = (acc0 + 2.0f*acc) * (1.0f/256.0f);
  float win = 0.5f - 0.5f*cz;
  outfr[t] = y*win;
}

// ---------------- final: harmonic synth + OLA gather ----------------
__global__ __launch_bounds__(256) void k_out(const float* __restrict__ f0,
    const float* __restrict__ ws, float* __restrict__ out){
  __shared__ float win2[256];
  __shared__ float c1s[BB*32];
  {
    int t = threadIdx.x;
    double a = (2.0*M_PI/256.0)*(double)t;
    float w = (float)(0.5 - 0.5*cos(a));
    win2[t] = w*w;
    if (t < BB*32) c1s[t] = ws[OFF_C1 + t];
  }
  __syncthreads();
  int idx = blockIdx.x*256 + threadIdx.x;
  if (idx >= BB*2*NSAMP) return;
  int m = idx % NSAMP;
  int bc = idx / NSAMP;
  int ch = bc & 1, b = bc >> 1;
  // f32 interp chain (bit-exact to numpy f32 elementwise)
  int i0,i1; float w,w1;
  up_coords(m,&i0,&i1,&w,&w1);
  const float* f0b = f0 + b*TT;
  float f0u = __fadd_rn(__fmul_rn(f0b[i0], w1), __fmul_rn(f0b[i1], w));
  const float* am = ws + OFF_AMP + b*TT;
  float oa = __fadd_rn(__fmul_rn(am[i0], w1), __fmul_rn(am[i1], w));
  const float* ha = ws + (ch ? OFF_HARMR : OFF_HARML) + (size_t)b*TT*NHARM;
  float tm = (float)m;
  float hsum = 0.0f;
  for (int k=1;k<=NHARM;k++){
    float instf = __fmul_rn(f0u, (float)k);          // RN32(f0_up*k), exact mask
    if (instf < 21600.0f){
      float a0 = ha[i0*NHARM + (k-1)], a1 = ha[i1*NHARM + (k-1)];
      float ak = __fadd_rn(__fmul_rn(a0, w1), __fmul_rn(a1, w));
      float ph = __fmul_rn(c1s[b*32 + (k-1)], tm);   // RN32(c1*t): exact f32 phase
      double rev = (double)ph * 0.15915494309189535; // /(2pi) in f64
      double fr2 = rev - floor(rev);
      float rad = (float)((fr2 - (fr2 >= 0.5 ? 1.0 : 0.0)) * 6.283185307179586);
      float s = sinf(rad);                            // sin(exact f32 phase)
      hsum = __fadd_rn(hsum, __fmul_rn(ak, s));
    }
  }
  float harm = __fmul_rn(hsum, oa);
  // noise OLA gather
  int p = m + 128;
  int fhi = min(p >> 6, NFRAMES-1);
  int flo = max((p - 192) >> 6, 0);
  const float* frb = ws + (ch ? OFF_FRR : OFF_FRL) + (size_t)b*NFRAMES*256;
  float nacc = 0.0f, wsum = 0.0f;
  for (int f=flo; f<=fhi; f++){
    int n = p - f*NHOPF;
    nacc += frb[f*256 + n];
    wsum += win2[n];
  }
  float noise = nacc / fmaxf(wsum, 1e-11f);
  out[idx] = __fadd_rn(harm, noise);
}

extern "C" void kernel_launch(void* const* d_in, const int* in_sizes, int n_in,
                              void* d_out, int out_size, void* d_ws, size_t ws_size,
                              hipStream_t stream){
  const float* f0  = (const float*)d_in[0];
  const float* ldb = (const float*)d_in[1];
  const float* vel = (const float*)d_in[2];
  const float* nL  = (const float*)d_in[3];
  const float* nR  = (const float*)d_in[4];
  const float* Wp1 = (const float*)d_in[5];
  const float* bp1 = (const float*)d_in[6];
  const float* Wp2 = (const float*)d_in[7];
  const float* bp2 = (const float*)d_in[8];
  const float* Wih = (const float*)d_in[9];
  const float* Whh = (const float*)d_in[10];
  const float* bih = (const float*)d_in[11];
  const float* bhh = (const float*)d_in[12];
  const float* Wpo = (const float*)d_in[13];
  const float* bpo = (const float*)d_in[14];
  const float* WhL = (const float*)d_in[15];
  const float* bhL = (const float*)d_in[16];
  const float* WhR = (const float*)d_in[17];
  const float* bhR = (const float*)d_in[18];
  const float* Wam = (const float*)d_in[19];
  const float* bam = (const float*)d_in[20];
  const float* WnL = (const float*)d_in[21];
  const float* bnL = (const float*)d_in[22];
  const float* WnR = (const float*)d_in[23];
  const float* bnR = (const float*)d_in[24];
  float* ws = (float*)d_ws;
  float* out = (float*)d_out;

  k_enc<<<(BB*TT+255)/256, 256, 0, stream>>>(f0, ldb, vel, ws+OFF_FEAT);
  k_mm<1><<<(BB*TT*128+255)/256, 256, 0, stream>>>(ws+OFF_FEAT, Wp1, bp1, ws+OFF_H1, BB*TT, 128, FEATD);
  k_mm<1><<<(BB*TT*128+255)/256, 256, 0, stream>>>(ws+OFF_H1, Wp2, bp2, ws+OFF_H2, BB*TT, 128, 128);
  k_mm<0><<<(BB*TT*192+255)/256, 256, 0, stream>>>(ws+OFF_H2, Wih, bih, ws+OFF_GI, BB*TT, 192, 128);
  k_gru<<<BB, 64, 0, stream>>>(ws+OFF_GI, Whh, bhh, ws+OFF_GOUT);
  k_mm<1><<<(BB*TT*128+255)/256, 256, 0, stream>>>(ws+OFF_GOUT, Wpo, bpo, ws+OFF_POST, BB*TT, 128, HID);
  k_heads<<<(BB*TT*323+255)/256, 256, 0, stream>>>(ws+OFF_POST, WhL,bhL, WhR,bhR, Wam,bam, WnL,bnL, WnR,bnR,
      ws+OFF_HARML, ws+OFF_HARMR, ws+OFF_AMP, ws+OFF_NMAGL, ws+OFF_NMAGR);
  dim3 gmf(BB, 32);
  k_meanf0_np<<<gmf, 256, 0, stream>>>(f0, ws);
  dim3 gs(BB*NFRAMES, 2);
  k_stft<<<gs, 64, 0, stream>>>(nL, nR, ws);
  k_istft<<<gs, 256, 0, stream>>>(ws);
  k_out<<<(BB*2*NSAMP+255)/256, 256, 0, stream>>>(f0, ws, out);
}

// Round 11
// 641.946 us; speedup vs baseline: 1.2048x; 1.0981x over previous
//
#include <hip/hip_runtime.h>
#include <math.h>

#ifndef M_PI
#define M_PI 3.14159265358979323846
#endif

#define BB 4
#define TT 500
#define NSAMP 120000
#define NHARM 32
#define NFFT 256
#define NBIN 129
#define NHOPF 64
#define NFRAMES 1876
#define HID 64
#define MLPD 128
#define FEATD 88

#define R_MAG ((float)(500.0/1876.0))
#define R_UP_F ((float)(500.0/120000.0))

// ---- workspace layout (float offsets) ----
// SPEC moved PAST the trunk (GI/GOUT live concurrently with stft in k_mid).
// istft is IN-PLACE (frame slot 258 floats: spec -> time-frame), so no
// separate FR region. Total 5974192 floats = 23.9 MB (known-safe <= 33.4).
#define OFF_HARML 0
#define OFF_HARMR 64000
#define OFF_AMP   128000
#define OFF_NMAGL 130000
#define OFF_NMAGR 388000
#define OFF_C1    646000            /* 128 floats: RN32(c32*mf32) per (b,k) */
#define OFF_FEAT  646128
#define OFF_H1    (OFF_FEAT+176000)
#define OFF_H2    (OFF_H1+256000)
#define OFF_GI    (OFF_H2+256000)
#define OFF_GOUT  (OFF_GI+384000)
#define OFF_POST  (OFF_GOUT+128000)
#define OFF_SPECL (OFF_POST+256000)              /* 2102128 */
#define OFF_SPECR (OFF_SPECL+4*NFRAMES*258)      /* +1936032 */
/* end = OFF_SPECR+1936032 = 5974192 floats */

// f32 upsample position/interp chain, bit-exact to numpy float32 elementwise
__device__ __forceinline__ void up_coords(int m, int* i0, int* i1, float* w, float* w1){
  float pos = __fadd_rn(__fmul_rn(__fadd_rn((float)m, 0.5f), R_UP_F), -0.5f);
  pos = fminf(fmaxf(pos, 0.0f), 499.0f);
  int a = (int)pos;
  *i0 = a; *i1 = min(a+1, TT-1);
  float ww = __fsub_rn(pos, (float)a);
  *w = ww; *w1 = __fsub_rn(1.0f, ww);
}
__device__ __forceinline__ float f0_up_elem(const float* __restrict__ f0s, int m){
  int i0,i1; float w,w1;
  up_coords(m,&i0,&i1,&w,&w1);
  return __fadd_rn(__fmul_rn(f0s[i0], w1), __fmul_rn(f0s[i1], w));
}

// ---------------- encoding ----------------
__global__ void k_enc(const float* __restrict__ f0, const float* __restrict__ ldb,
                      const float* __restrict__ vel, float* __restrict__ feat){
  int idx = blockIdx.x*blockDim.x + threadIdx.x;
  if (idx >= BB*TT) return;
  int b = idx / TT;
  float f = f0[idx];
  float gate = (f > 0.0f) ? 1.0f : 0.0f;
  float fs = fmaxf(f, 20.0f);
  float fn = (logf(fs) - (float)2.995732273553991) / (float)5.5214609178622464;
  fn = fminf(fmaxf(fn, 0.0f), 1.0f);
  float ln = fminf(fmaxf((ldb[idx] + 80.0f) / 80.0f, 0.0f), 1.0f);
  float vn = fminf(fmaxf(vel[b] / 7.0f, 0.0f), 1.0f);
  float* o = feat + idx*FEATD;
  #pragma unroll 4
  for (int i=1;i<=32;i++){
    float ang = (float)M_PI * (float)i * fn;
    o[2*i-2] = sinf(ang)*gate;
    o[2*i-1] = cosf(ang)*gate;
  }
  #pragma unroll
  for (int i=1;i<=8;i++){
    float ang = (float)M_PI * (float)i * ln;
    o[64+2*i-2] = sinf(ang);
    o[64+2*i-1] = cosf(ang);
  }
  #pragma unroll
  for (int i=1;i<=4;i++){
    float ang = (float)M_PI * (float)i * vn;
    o[80+2*i-2] = sinf(ang);
    o[80+2*i-1] = cosf(ang);
  }
}

// ---------------- generic matmul: out = act(in @ W^T + b) ----------------
template<int ACT>
__global__ void k_mm(const float* __restrict__ in, const float* __restrict__ W,
                     const float* __restrict__ bias, float* __restrict__ out,
                     int R, int C, int IN){
  int idx = blockIdx.x*blockDim.x + threadIdx.x;
  if (idx >= R*C) return;
  int r = idx / C, c = idx - r*C;
  const float* ip = in + r*IN;
  const float* wp = W + c*IN;
  float acc = bias[c];
  #pragma unroll 8
  for (int i=0;i<IN;i++) acc = fmaf(ip[i], wp[i], acc);
  if (ACT==1) acc = fmaxf(acc, 0.0f);
  out[idx] = acc;
}

// numpy-exact pairwise block sum (leaf of the depth-10 perfect tree)
__device__ float np_block_sum(const float* __restrict__ f0s, int off, int n, float kf){
  float r[8];
  #pragma unroll
  for (int j=0;j<8;j++) r[j] = __fmul_rn(f0_up_elem(f0s, off+j), kf);
  int lim = n - (n & 7);
  int i = 8;
  for (; i<lim; i+=8){
    #pragma unroll
    for (int j=0;j<8;j++)
      r[j] = __fadd_rn(r[j], __fmul_rn(f0_up_elem(f0s, off+i+j), kf));
  }
  float res = __fadd_rn(__fadd_rn(__fadd_rn(r[0],r[1]), __fadd_rn(r[2],r[3])),
                        __fadd_rn(__fadd_rn(r[4],r[5]), __fadd_rn(r[6],r[7])));
  for (; i<n; i++)
    res = __fadd_rn(res, __fmul_rn(f0_up_elem(f0s, off+i), kf));
  return res;
}

// ---------------- fused mid: GRU + STFT + meanf0 (block-type dispatch) ----------------
// GRU is latency-bound on 4 lonely blocks (5 prior variants all ~1500cyc/iter);
// stft (noise-only) and meanf0 (f0-only) are data-independent of it -> run
// them on the otherwise-idle 252 CUs inside the SAME kernel.
#define MID_GRU   BB                        /* blocks 0..3 */
#define MID_MF    (MID_GRU + BB*32)         /* 4..131 : meanf0 (b,k) */
#define STFT_JOBS (2*BB*NFRAMES)            /* 15008 frame-jobs */
#define MID_STFT_BLOCKS ((STFT_JOBS+5)/6)   /* 2502, 6 frames/block */
#define MID_BLOCKS (MID_MF + MID_STFT_BLOCKS)

__global__ __launch_bounds__(384) void k_mid(
    const float* __restrict__ gi, const float* __restrict__ Whh,
    const float* __restrict__ bhh, float* __restrict__ gout,
    const float* __restrict__ f0, const float* __restrict__ nL,
    const float* __restrict__ nR, float* __restrict__ ws){
  __shared__ __align__(16) float sh[2048];
  int blk = blockIdx.x;
  int tid = threadIdx.x;

  if (blk < MID_GRU){
    // ---- GRU: 6 waves; thread (p = tid/192, o = tid%192) does a 32-term
    // half-dot for output o. 32 resident weights/lane (no remat possible).
    // h lane-local via readlane; halves combined in dbuf LDS; 1 barrier/iter.
    int b = blk;
    int p = tid / 192;              // wave-uniform (0 or 1)
    int o = tid - p*192;
    int g = o >> 6, j = o & 63;
    float w[32];
    const float* wrow = Whh + (size_t)(g*64+j)*64 + p*32;
    #pragma unroll
    for (int i=0;i<8;i++){
      float4 v = *(const float4*)(wrow + i*4);
      w[4*i]=v.x; w[4*i+1]=v.y; w[4*i+2]=v.z; w[4*i+3]=v.w;
    }
    int lbase = __builtin_amdgcn_readfirstlane(p*32);
    float br = bhh[j], bz = bhh[64+j], bn = bhh[128+j];
    const float* gp = gi + (size_t)b*TT*192 + j;
    float* op = gout + (size_t)b*TT*64 + j;
    float hreg = 0.0f;
    float gr0 = gp[0],   gz0 = gp[64],  gn0 = gp[128];
    float gr1 = gp[192], gz1 = gp[256], gn1 = gp[320];
    for (int t=0;t<TT;t++){
      float acc = 0.f;
      #pragma unroll
      for (int ii=0;ii<32;ii++){
        float hi = __uint_as_float(__builtin_amdgcn_readlane(__float_as_uint(hreg), lbase+ii));
        acc = fmaf(w[ii], hi, acc);
      }
      float* ab = sh + (t&1)*384;
      ab[tid] = acc;
      __syncthreads();
      float ar = __fadd_rn(ab[j],     ab[192+j]);
      float az = __fadd_rn(ab[64+j],  ab[256+j]);
      float an = __fadd_rn(ab[128+j], ab[320+j]);
      int tn = min(t+2, TT-1);                 // prefetch AFTER barrier ->
      float gr2 = gp[tn*192];                  // >=1 iter old at next drain
      float gz2 = gp[tn*192+64];
      float gn2 = gp[tn*192+128];
      float r = 1.0f/(1.0f+expf(-(gr0+ar+br)));
      float z = 1.0f/(1.0f+expf(-(gz0+az+bz)));
      float n = tanhf(gn0 + r*(an+bn));
      hreg = (1.0f - z)*n + z*hreg;            // identical on all 6 waves
      if (tid < 64) op[t*64] = hreg;
      gr0=gr1; gz0=gz1; gn0=gn1;
      gr1=gr2; gz1=gz2; gn1=gn2;
    }
  } else if (blk < MID_MF){
    // ---- meanf0 (bit-exact numpy pairwise tree), threads<256 active
    int bk = blk - MID_GRU;
    int b = bk >> 5, k = bk & 31;
    float kf = (float)(k+1);
    float* f0s = sh;            // [500]
    float* red = sh + 512;      // [256]
    for (int i=tid;i<TT;i+=384) f0s[i] = f0[b*TT+i];
    __syncthreads();
    if (tid < 256){
      float lv[4];
      #pragma unroll
      for (int q=0;q<4;q++){
        int leafIdx = tid*4 + q;
        int off = 0, n = NSAMP;
        #pragma unroll
        for (int lvl=9; lvl>=0; --lvl){
          int n2 = (n>>1); n2 -= (n2 & 7);
          if ((leafIdx >> lvl) & 1){ off += n2; n -= n2; } else { n = n2; }
        }
        lv[q] = np_block_sum(f0s, off, n, kf);
      }
      red[tid] = __fadd_rn(__fadd_rn(lv[0],lv[1]), __fadd_rn(lv[2],lv[3]));
    }
    __syncthreads();
    for (int cnt=256; cnt>1; cnt>>=1){
      int half = cnt>>1;
      float v = 0.0f;
      if (tid < half) v = __fadd_rn(red[2*tid], red[2*tid+1]);
      __syncthreads();
      if (tid < half) red[tid] = v;
      __syncthreads();
    }
    if (tid==0){
      float mf = __fdiv_rn(red[0], 120000.0f);
      float c1 = __fmul_rn((float)(2.0*M_PI/48000.0), mf);
      ws[OFF_C1 + b*32 + k] = c1;
    }
  } else {
    // ---- STFT: 6 frames per block (one wave each), shared twiddle table
    int base = (blk - MID_MF)*6;
    int sub = tid >> 6;
    int j = tid & 63;
    float2* tw = (float2*)sh;               // [256] (2KB)
    float* frs = sh + 512 + sub*256;        // [6][256]
    if (tid < 256){
      double a = (2.0*M_PI/256.0)*(double)tid;
      tw[tid] = make_float2((float)cos(a), (float)sin(a));
    }
    int jid = base + sub;
    bool act = jid < STFT_JOBS;
    int b=0, f=0; const float* x = nL;
    if (act){
      int ch = jid / (BB*NFRAMES);
      int rem = jid - ch*(BB*NFRAMES);
      b = rem / NFRAMES; f = rem - b*NFRAMES;
      x = (ch ? nR : nL) + (size_t)b*NSAMP;
      for (int n=j;n<256;n+=64){
        double a = (2.0*M_PI/256.0)*(double)n;
        int xi = f*NHOPF + n - 128;
        xi = xi < 0 ? -xi : xi;
        xi = xi >= NSAMP ? 2*(NSAMP-1)-xi : xi;
        float wnd = (float)(0.5 - 0.5*cos(a));
        frs[n] = x[xi]*wnd;
      }
    }
    __syncthreads();
    if (act){
      int ch = jid / (BB*NFRAMES);
      float* spec = ws + (ch ? OFF_SPECR : OFF_SPECL) + (size_t)(b*NFRAMES+f)*258;
      float re0=0.f, im0=0.f, re1=0.f, im1=0.f;
      int m0 = 0;
      #pragma unroll 4
      for (int n=0;n<256;n++){
        float fv = frs[n];
        int m1 = (m0 + ((n&3)<<6)) & 255;
        float2 t0 = tw[m0], t1 = tw[m1];
        re0 = fmaf(fv, t0.x, re0); im0 = fmaf(-fv, t0.y, im0);
        re1 = fmaf(fv, t1.x, re1); im1 = fmaf(-fv, t1.y, im1);
        m0 = (m0 + j) & 255;
      }
      float pq = frs[j] + frs[j+64] + frs[j+128] + frs[j+192];
      pq = (j & 1) ? -pq : pq;
      for (int o2=32;o2>0;o2>>=1) pq += __shfl_down(pq, o2, 64);
      spec[2*j]   = re0; spec[2*j+1]   = im0;
      spec[2*(j+64)] = re1; spec[2*(j+64)+1] = im1;
      if (j==0){ spec[256] = pq; spec[257] = 0.0f; }
    }
  }
}

// ---------------- heads ----------------
__global__ void k_heads(const float* __restrict__ post,
  const float* __restrict__ WhL, const float* __restrict__ bhL,
  const float* __restrict__ WhR, const float* __restrict__ bhR,
  const float* __restrict__ Wam, const float* __restrict__ bam,
  const float* __restrict__ WnL, const float* __restrict__ bnL,
  const float* __restrict__ WnR, const float* __restrict__ bnR,
  float* __restrict__ harmL, float* __restrict__ harmR, float* __restrict__ amp,
  float* __restrict__ nmagL, float* __restrict__ nmagR){
  int idx = blockIdx.x*blockDim.x + threadIdx.x;
  if (idx >= BB*TT*323) return;
  int r = idx / 323, c = idx - r*323;
  const float* W; const float* bb; float* o; int oc, ow; bool sp=false;
  if (c < 32)      { W=WhL; bb=bhL; o=harmL; oc=c;     ow=32; }
  else if (c < 64) { W=WhR; bb=bhR; o=harmR; oc=c-32;  ow=32; }
  else if (c == 64){ W=Wam; bb=bam; o=amp;   oc=0;     ow=1; sp=true; }
  else if (c < 194){ W=WnL; bb=bnL; o=nmagL; oc=c-65;  ow=129; }
  else             { W=WnR; bb=bnR; o=nmagR; oc=c-194; ow=129; }
  const float* ip = post + r*MLPD;
  const float* wp = W + oc*MLPD;
  float acc = bb[oc];
  #pragma unroll 8
  for (int i=0;i<MLPD;i++) acc = fmaf(ip[i], wp[i], acc);
  float v;
  if (sp) v = fmaxf(acc, 0.0f) + log1pf(expf(-fabsf(acc)));   // softplus (stable)
  else    v = 1.0f/(1.0f+expf(-acc));                          // sigmoid
  o[r*ow + oc] = v;
}

// ---------------- mag filter + irfft + window (IN-PLACE on spec slot) ----------------
__global__ __launch_bounds__(256) void k_istft(float* __restrict__ ws){
  int fr = blockIdx.x;
  int ch = blockIdx.y;
  int b = fr / NFRAMES, f = fr - b*NFRAMES;
  float* spec = ws + (ch ? OFF_SPECR : OFF_SPECL) + (size_t)fr*258;
  const float* nmag = ws + (ch ? OFF_NMAGR : OFF_NMAGL) + (size_t)b*TT*NBIN;
  int t = threadIdx.x;
  __shared__ float2 tw[256];
  __shared__ float2 mx[NBIN];
  double a = (2.0*M_PI/256.0)*(double)t;
  float cz = (float)cos(a), sz = (float)sin(a);
  tw[t] = make_float2(cz, sz);
  if (t < NBIN){
    float pos = ((float)f + 0.5f) * R_MAG - 0.5f;
    pos = fminf(fmaxf(pos, 0.0f), 499.0f);
    int i0 = (int)pos, i1 = min(i0+1, TT-1);
    float w = pos - (float)i0;
    float mg = nmag[i0*NBIN + t]*(1.0f-w) + nmag[i1*NBIN + t]*w;
    mx[t] = make_float2(spec[2*t]*mg, spec[2*t+1]*mg);
  }
  __syncthreads();                    // all spec reads complete -> in-place safe
  float acc0 = mx[0].x + ((t&1) ? -mx[128].x : mx[128].x);
  float acc = 0.0f;
  int mi = t;
  #pragma unroll 4
  for (int k=1;k<128;k++){
    float2 v = mx[k];
    float2 tk = tw[mi];
    acc = fmaf(v.x, tk.x, acc);
    acc = fmaf(-v.y, tk.y, acc);
    mi = (mi + t) & 255;
  }
  float y = (acc0 + 2.0f*acc) * (1.0f/256.0f);
  float win = 0.5f - 0.5f*cz;
  spec[t] = y*win;                    // overwrite own slot (258-stride frames)
}

// ---------------- final: harmonic synth + OLA gather ----------------
__global__ __launch_bounds__(256) void k_out(const float* __restrict__ f0,
    const float* __restrict__ ws, float* __restrict__ out){
  __shared__ float win2[256];
  __shared__ float c1s[BB*32];
  {
    int t = threadIdx.x;
    double a = (2.0*M_PI/256.0)*(double)t;
    float w = (float)(0.5 - 0.5*cos(a));
    win2[t] = w*w;
    if (t < BB*32) c1s[t] = ws[OFF_C1 + t];
  }
  __syncthreads();
  int idx = blockIdx.x*256 + threadIdx.x;
  if (idx >= BB*2*NSAMP) return;
  int m = idx % NSAMP;
  int bc = idx / NSAMP;
  int ch = bc & 1, b = bc >> 1;
  int i0,i1; float w,w1;
  up_coords(m,&i0,&i1,&w,&w1);
  const float* f0b = f0 + b*TT;
  float f0u = __fadd_rn(__fmul_rn(f0b[i0], w1), __fmul_rn(f0b[i1], w));
  const float* am = ws + OFF_AMP + b*TT;
  float oa = __fadd_rn(__fmul_rn(am[i0], w1), __fmul_rn(am[i1], w));
  const float* ha = ws + (ch ? OFF_HARMR : OFF_HARML) + (size_t)b*TT*NHARM;
  float tm = (float)m;
  float hsum = 0.0f;
  for (int k=1;k<=NHARM;k++){
    float instf = __fmul_rn(f0u, (float)k);          // RN32(f0_up*k), exact mask
    if (instf < 21600.0f){
      float a0 = ha[i0*NHARM + (k-1)], a1 = ha[i1*NHARM + (k-1)];
      float ak = __fadd_rn(__fmul_rn(a0, w1), __fmul_rn(a1, w));
      float ph = __fmul_rn(c1s[b*32 + (k-1)], tm);   // RN32(c1*t): exact f32 phase
      double rev = (double)ph * 0.15915494309189535;
      double fr2 = rev - floor(rev);
      float rad = (float)((fr2 - (fr2 >= 0.5 ? 1.0 : 0.0)) * 6.283185307179586);
      float s = sinf(rad);
      hsum = __fadd_rn(hsum, __fmul_rn(ak, s));
    }
  }
  float harm = __fmul_rn(hsum, oa);
  // noise OLA gather (frames now stride-258, in-place region)
  int p = m + 128;
  int fhi = min(p >> 6, NFRAMES-1);
  int flo = max((p - 192) >> 6, 0);
  const float* frb = ws + (ch ? OFF_SPECR : OFF_SPECL) + (size_t)b*NFRAMES*258;
  float nacc = 0.0f, wsum = 0.0f;
  for (int f=flo; f<=fhi; f++){
    int n = p - f*NHOPF;
    nacc += frb[f*258 + n];
    wsum += win2[n];
  }
  float noise = nacc / fmaxf(wsum, 1e-11f);
  out[idx] = __fadd_rn(harm, noise);
}

extern "C" void kernel_launch(void* const* d_in, const int* in_sizes, int n_in,
                              void* d_out, int out_size, void* d_ws, size_t ws_size,
                              hipStream_t stream){
  const float* f0  = (const float*)d_in[0];
  const float* ldb = (const float*)d_in[1];
  const float* vel = (const float*)d_in[2];
  const float* nL  = (const float*)d_in[3];
  const float* nR  = (const float*)d_in[4];
  const float* Wp1 = (const float*)d_in[5];
  const float* bp1 = (const float*)d_in[6];
  const float* Wp2 = (const float*)d_in[7];
  const float* bp2 = (const float*)d_in[8];
  const float* Wih = (const float*)d_in[9];
  const float* Whh = (const float*)d_in[10];
  const float* bih = (const float*)d_in[11];
  const float* bhh = (const float*)d_in[12];
  const float* Wpo = (const float*)d_in[13];
  const float* bpo = (const float*)d_in[14];
  const float* WhL = (const float*)d_in[15];
  const float* bhL = (const float*)d_in[16];
  const float* WhR = (const float*)d_in[17];
  const float* bhR = (const float*)d_in[18];
  const float* Wam = (const float*)d_in[19];
  const float* bam = (const float*)d_in[20];
  const float* WnL = (const float*)d_in[21];
  const float* bnL = (const float*)d_in[22];
  const float* WnR = (const float*)d_in[23];
  const float* bnR = (const float*)d_in[24];
  float* ws = (float*)d_ws;
  float* out = (float*)d_out;

  k_enc<<<(BB*TT+255)/256, 256, 0, stream>>>(f0, ldb, vel, ws+OFF_FEAT);
  k_mm<1><<<(BB*TT*128+255)/256, 256, 0, stream>>>(ws+OFF_FEAT, Wp1, bp1, ws+OFF_H1, BB*TT, 128, FEATD);
  k_mm<1><<<(BB*TT*128+255)/256, 256, 0, stream>>>(ws+OFF_H1, Wp2, bp2, ws+OFF_H2, BB*TT, 128, 128);
  k_mm<0><<<(BB*TT*192+255)/256, 256, 0, stream>>>(ws+OFF_H2, Wih, bih, ws+OFF_GI, BB*TT, 192, 128);
  k_mid<<<MID_BLOCKS, 384, 0, stream>>>(ws+OFF_GI, Whh, bhh, ws+OFF_GOUT, f0, nL, nR, ws);
  k_mm<1><<<(BB*TT*128+255)/256, 256, 0, stream>>>(ws+OFF_GOUT, Wpo, bpo, ws+OFF_POST, BB*TT, 128, HID);
  k_heads<<<(BB*TT*323+255)/256, 256, 0, stream>>>(ws+OFF_POST, WhL,bhL, WhR,bhR, Wam,bam, WnL,bnL, WnR,bnR,
      ws+OFF_HARML, ws+OFF_HARMR, ws+OFF_AMP, ws+OFF_NMAGL, ws+OFF_NMAGR);
  dim3 gs(BB*NFRAMES, 2);
  k_istft<<<gs, 256, 0, stream>>>(ws);
  k_out<<<(BB*2*NSAMP+255)/256, 256, 0, stream>>>(f0, ws, out);
}

// Round 12
// 559.545 us; speedup vs baseline: 1.3823x; 1.1473x over previous
//
#include <hip/hip_runtime.h>
#include <math.h>

#ifndef M_PI
#define M_PI 3.14159265358979323846
#endif

#define BB 4
#define TT 500
#define NSAMP 120000
#define NHARM 32
#define NFFT 256
#define NBIN 129
#define NHOPF 64
#define NFRAMES 1876
#define HID 64
#define MLPD 128
#define FEATD 88

#define R_MAG ((float)(500.0/1876.0))
#define R_UP_F ((float)(500.0/120000.0))

// ---- workspace layout (float offsets) ----
#define OFF_HARML 0
#define OFF_HARMR 64000
#define OFF_AMP   128000
#define OFF_NMAGL 130000
#define OFF_NMAGR 388000
#define OFF_C1    646000            /* 128 floats: RN32(c32*mf32) per (b,k) */
#define OFF_H1    646128
#define OFF_GI    (OFF_H1+256000)
#define OFF_GOUT  (OFF_GI+384000)
#define OFF_SPECL (OFF_GOUT+128000)              /* spec/frames, in-place istft */
#define OFF_SPECR (OFF_SPECL+4*NFRAMES*258)
/* end = OFF_SPECR+1936032 = 5286160 floats = 21.1 MB */

// f32 upsample position/interp chain, bit-exact to numpy float32 elementwise
__device__ __forceinline__ void up_coords(int m, int* i0, int* i1, float* w, float* w1){
  float pos = __fadd_rn(__fmul_rn(__fadd_rn((float)m, 0.5f), R_UP_F), -0.5f);
  pos = fminf(fmaxf(pos, 0.0f), 499.0f);
  int a = (int)pos;
  *i0 = a; *i1 = min(a+1, TT-1);
  float ww = __fsub_rn(pos, (float)a);
  *w = ww; *w1 = __fsub_rn(1.0f, ww);
}
__device__ __forceinline__ float f0_up_elem(const float* __restrict__ f0s, int m){
  int i0,i1; float w,w1;
  up_coords(m,&i0,&i1,&w,&w1);
  return __fadd_rn(__fmul_rn(f0s[i0], w1), __fmul_rn(f0s[i1], w));
}

// ---------------- fused encoding + pre1 matmul ----------------
// Block = one (b,t) row. Phase1: threads 0..87 compute feat elems (identical
// expressions to the original k_enc -> bit-identical). Phase2: 128 threads
// each compute one H1 col with the exact sequential i=0..87 fmaf chain.
__global__ __launch_bounds__(128) void k_encmm(const float* __restrict__ f0,
    const float* __restrict__ ldb, const float* __restrict__ vel,
    const float* __restrict__ Wp1, const float* __restrict__ bp1,
    float* __restrict__ h1){
  int row = blockIdx.x;                 // b*TT + t
  int b = row / TT;
  int tid = threadIdx.x;
  __shared__ float feat[FEATD];
  if (tid < FEATD){
    float f = f0[row];
    float gate = (f > 0.0f) ? 1.0f : 0.0f;
    float fs = fmaxf(f, 20.0f);
    float fn = (logf(fs) - (float)2.995732273553991) / (float)5.5214609178622464;
    fn = fminf(fmaxf(fn, 0.0f), 1.0f);
    float ln = fminf(fmaxf((ldb[row] + 80.0f) / 80.0f, 0.0f), 1.0f);
    float vn = fminf(fmaxf(vel[b] / 7.0f, 0.0f), 1.0f);
    float norm; int i; float g2 = 1.0f;
    if (tid < 64){ i = (tid>>1) + 1; norm = fn; g2 = gate; }
    else if (tid < 80){ i = ((tid-64)>>1) + 1; norm = ln; }
    else { i = ((tid-80)>>1) + 1; norm = vn; }
    float ang = (float)M_PI * (float)i * norm;
    feat[tid] = ((tid & 1) ? cosf(ang) : sinf(ang)) * g2;
  }
  __syncthreads();
  const float* wp = Wp1 + tid*FEATD;
  float acc = bp1[tid];
  #pragma unroll 8
  for (int i=0;i<FEATD;i++) acc = fmaf(feat[i], wp[i], acc);
  h1[(size_t)row*MLPD + tid] = fmaxf(acc, 0.0f);
}

// ---------------- fused pre2 matmul + gi matmul ----------------
__global__ __launch_bounds__(192) void k_mm2gi(const float* __restrict__ h1,
    const float* __restrict__ Wp2, const float* __restrict__ bp2,
    const float* __restrict__ Wih, const float* __restrict__ bih,
    float* __restrict__ gi){
  int row = blockIdx.x;
  int tid = threadIdx.x;
  __shared__ float h1s[MLPD];
  __shared__ float h2s[MLPD];
  if (tid < MLPD) h1s[tid] = h1[(size_t)row*MLPD + tid];
  __syncthreads();
  if (tid < MLPD){
    const float* wp = Wp2 + tid*MLPD;
    float acc = bp2[tid];
    #pragma unroll 8
    for (int i=0;i<MLPD;i++) acc = fmaf(h1s[i], wp[i], acc);
    h2s[tid] = fmaxf(acc, 0.0f);
  }
  __syncthreads();
  const float* wp = Wih + tid*MLPD;
  float acc = bih[tid];
  #pragma unroll 8
  for (int i=0;i<MLPD;i++) acc = fmaf(h2s[i], wp[i], acc);
  gi[(size_t)row*192 + tid] = acc;
}

// numpy-exact pairwise block sum (leaf of the depth-10 perfect tree)
__device__ float np_block_sum(const float* __restrict__ f0s, int off, int n, float kf){
  float r[8];
  #pragma unroll
  for (int j=0;j<8;j++) r[j] = __fmul_rn(f0_up_elem(f0s, off+j), kf);
  int lim = n - (n & 7);
  int i = 8;
  for (; i<lim; i+=8){
    #pragma unroll
    for (int j=0;j<8;j++)
      r[j] = __fadd_rn(r[j], __fmul_rn(f0_up_elem(f0s, off+i+j), kf));
  }
  float res = __fadd_rn(__fadd_rn(__fadd_rn(r[0],r[1]), __fadd_rn(r[2],r[3])),
                        __fadd_rn(__fadd_rn(r[4],r[5]), __fadd_rn(r[6],r[7])));
  for (; i<n; i++)
    res = __fadd_rn(res, __fmul_rn(f0_up_elem(f0s, off+i), kf));
  return res;
}

// ---------------- fused mid: GRU + STFT + meanf0 ----------------
#define MID_GRU   BB
#define MID_MF    (MID_GRU + BB*32)
#define STFT_JOBS (2*BB*NFRAMES)
#define MID_STFT_BLOCKS ((STFT_JOBS+5)/6)
#define MID_BLOCKS (MID_MF + MID_STFT_BLOCKS)

#define RL(x,l) __uint_as_float(__builtin_amdgcn_readlane(__float_as_uint(x), (l)))

__global__ __launch_bounds__(384) void k_mid(
    const float* __restrict__ gi, const float* __restrict__ Whh,
    const float* __restrict__ bhh, float* __restrict__ gout,
    const float* __restrict__ f0, const float* __restrict__ nL,
    const float* __restrict__ nR, float* __restrict__ ws){
  __shared__ __align__(16) float sh[8192];     // 32 KB
  int blk = blockIdx.x;
  int tid = threadIdx.x;

  if (blk < MID_GRU){
    // ---- GRU: SINGLE wave, zero barriers, STORE-FREE inner loop.
    // r10 post-mortem: the in-loop gout store entered the vmcnt FIFO, so
    // every iteration's s_waitcnt for the prefetch regs also waited the
    // previous store's ack (~hundreds cyc). Here h-history goes to LDS
    // (lgkm counter) in 128-step chunks, flushed 4x with b128 stores.
    // Dot = 12 parallel 16-deep fmaf chains (4-acc split per gate; r11
    // proved dot-order perturbations don't move absmax).
    if (tid >= 64) return;
    int b = blk;
    int j = tid;
    float wr[64], wz[64], wn[64];
    #pragma unroll
    for (int i=0;i<16;i++){
      float4 a = *(const float4*)(Whh + (size_t)(j)*64     + i*4);
      float4 c = *(const float4*)(Whh + (size_t)(64+j)*64  + i*4);
      float4 d = *(const float4*)(Whh + (size_t)(128+j)*64 + i*4);
      wr[4*i]=a.x; wr[4*i+1]=a.y; wr[4*i+2]=a.z; wr[4*i+3]=a.w;
      wz[4*i]=c.x; wz[4*i+1]=c.y; wz[4*i+2]=c.z; wz[4*i+3]=c.w;
      wn[4*i]=d.x; wn[4*i+1]=d.y; wn[4*i+2]=d.z; wn[4*i+3]=d.w;
    }
    float br = bhh[j], bz = bhh[64+j], bn = bhh[128+j];
    const float* gp = gi + (size_t)b*TT*192 + j;
    float* op = gout + (size_t)b*TT*64;
    float hreg = 0.0f;
    float gr0 = gp[0],   gz0 = gp[64],  gn0 = gp[128];
    float gr1 = gp[192], gz1 = gp[256], gn1 = gp[320];
    for (int t=0;t<TT;t++){
      int tn = min(t+2, TT-1);
      float gr2 = gp[tn*192], gz2 = gp[tn*192+64], gn2 = gp[tn*192+128];
      float ar0=0.f,ar1=0.f,ar2=0.f,ar3=0.f;
      float az0=0.f,az1=0.f,az2=0.f,az3=0.f;
      float an0=0.f,an1=0.f,an2=0.f,an3=0.f;
      #pragma unroll
      for (int i=0;i<16;i++){
        float h0 = RL(hreg, i), h1v = RL(hreg, 16+i);
        float h2v = RL(hreg, 32+i), h3v = RL(hreg, 48+i);
        ar0 = fmaf(wr[i],    h0,  ar0); ar1 = fmaf(wr[16+i], h1v, ar1);
        ar2 = fmaf(wr[32+i], h2v, ar2); ar3 = fmaf(wr[48+i], h3v, ar3);
        az0 = fmaf(wz[i],    h0,  az0); az1 = fmaf(wz[16+i], h1v, az1);
        az2 = fmaf(wz[32+i], h2v, az2); az3 = fmaf(wz[48+i], h3v, az3);
        an0 = fmaf(wn[i],    h0,  an0); an1 = fmaf(wn[16+i], h1v, an1);
        an2 = fmaf(wn[32+i], h2v, an2); an3 = fmaf(wn[48+i], h3v, an3);
      }
      float ar = __fadd_rn(__fadd_rn(ar0,ar1), __fadd_rn(ar2,ar3));
      float az = __fadd_rn(__fadd_rn(az0,az1), __fadd_rn(az2,az3));
      float an = __fadd_rn(__fadd_rn(an0,an1), __fadd_rn(an2,an3));
      float r = 1.0f/(1.0f+expf(-(gr0+ar+br)));
      float z = 1.0f/(1.0f+expf(-(gz0+az+bz)));
      float n = tanhf(gn0 + r*(an+bn));
      hreg = (1.0f - z)*n + z*hreg;
      int tt = t & 127;
      sh[tt*64 + j] = hreg;                   // LDS (lgkm), not vmem
      if (tt == 127 || t == TT-1){
        int base_t = t - tt;
        int per = (tt+1);                     // dwords/lane = (tt+1)*64/64
        int nb = per >> 2;                    // b128s per lane (32 or 29)
        float* dst = op + base_t*64 + j*per;
        #pragma unroll 4
        for (int q=0;q<nb;q++){
          float4 v = *(float4*)&sh[j*per + q*4];
          *(float4*)&dst[q*4] = v;
        }
      }
      gr0=gr1; gz0=gz1; gn0=gn1;
      gr1=gr2; gz1=gz2; gn1=gn2;
    }
  } else if (blk < MID_MF){
    // ---- meanf0 (bit-exact numpy pairwise tree)
    int bk = blk - MID_GRU;
    int b = bk >> 5, k = bk & 31;
    float kf = (float)(k+1);
    float* f0s = sh;
    float* red = sh + 512;
    for (int i=tid;i<TT;i+=384) f0s[i] = f0[b*TT+i];
    __syncthreads();
    if (tid < 256){
      float lv[4];
      #pragma unroll
      for (int q=0;q<4;q++){
        int leafIdx = tid*4 + q;
        int off = 0, n = NSAMP;
        #pragma unroll
        for (int lvl=9; lvl>=0; --lvl){
          int n2 = (n>>1); n2 -= (n2 & 7);
          if ((leafIdx >> lvl) & 1){ off += n2; n -= n2; } else { n = n2; }
        }
        lv[q] = np_block_sum(f0s, off, n, kf);
      }
      red[tid] = __fadd_rn(__fadd_rn(lv[0],lv[1]), __fadd_rn(lv[2],lv[3]));
    }
    __syncthreads();
    for (int cnt=256; cnt>1; cnt>>=1){
      int half = cnt>>1;
      float v = 0.0f;
      if (tid < half) v = __fadd_rn(red[2*tid], red[2*tid+1]);
      __syncthreads();
      if (tid < half) red[tid] = v;
      __syncthreads();
    }
    if (tid==0){
      float mf = __fdiv_rn(red[0], 120000.0f);
      float c1 = __fmul_rn((float)(2.0*M_PI/48000.0), mf);
      ws[OFF_C1 + b*32 + k] = c1;
    }
  } else {
    // ---- STFT: 6 frames per block (one wave each), shared twiddle table
    int base = (blk - MID_MF)*6;
    int sub = tid >> 6;
    int j = tid & 63;
    float2* tw = (float2*)sh;
    float* frs = sh + 512 + sub*256;
    if (tid < 256){
      double a = (2.0*M_PI/256.0)*(double)tid;
      tw[tid] = make_float2((float)cos(a), (float)sin(a));
    }
    int jid = base + sub;
    bool act = jid < STFT_JOBS;
    int b=0, f=0; const float* x = nL;
    if (act){
      int ch = jid / (BB*NFRAMES);
      int rem = jid - ch*(BB*NFRAMES);
      b = rem / NFRAMES; f = rem - b*NFRAMES;
      x = (ch ? nR : nL) + (size_t)b*NSAMP;
      for (int n=j;n<256;n+=64){
        double a = (2.0*M_PI/256.0)*(double)n;
        int xi = f*NHOPF + n - 128;
        xi = xi < 0 ? -xi : xi;
        xi = xi >= NSAMP ? 2*(NSAMP-1)-xi : xi;
        float wnd = (float)(0.5 - 0.5*cos(a));
        frs[n] = x[xi]*wnd;
      }
    }
    __syncthreads();
    if (act){
      int ch = jid / (BB*NFRAMES);
      float* spec = ws + (ch ? OFF_SPECR : OFF_SPECL) + (size_t)(b*NFRAMES+f)*258;
      float re0=0.f, im0=0.f, re1=0.f, im1=0.f;
      int m0 = 0;
      #pragma unroll 4
      for (int n=0;n<256;n++){
        float fv = frs[n];
        int m1 = (m0 + ((n&3)<<6)) & 255;
        float2 t0 = tw[m0], t1 = tw[m1];
        re0 = fmaf(fv, t0.x, re0); im0 = fmaf(-fv, t0.y, im0);
        re1 = fmaf(fv, t1.x, re1); im1 = fmaf(-fv, t1.y, im1);
        m0 = (m0 + j) & 255;
      }
      float pq = frs[j] + frs[j+64] + frs[j+128] + frs[j+192];
      pq = (j & 1) ? -pq : pq;
      for (int o2=32;o2>0;o2>>=1) pq += __shfl_down(pq, o2, 64);
      spec[2*j]   = re0; spec[2*j+1]   = im0;
      spec[2*(j+64)] = re1; spec[2*(j+64)+1] = im1;
      if (j==0){ spec[256] = pq; spec[257] = 0.0f; }
    }
  }
}

// ---------------- fused post matmul + heads ----------------
__global__ __launch_bounds__(128) void k_posthead(const float* __restrict__ gout,
  const float* __restrict__ Wpo, const float* __restrict__ bpo,
  const float* __restrict__ WhL, const float* __restrict__ bhL,
  const float* __restrict__ WhR, const float* __restrict__ bhR,
  const float* __restrict__ Wam, const float* __restrict__ bam,
  const float* __restrict__ WnL, const float* __restrict__ bnL,
  const float* __restrict__ WnR, const float* __restrict__ bnR,
  float* __restrict__ harmL, float* __restrict__ harmR, float* __restrict__ amp,
  float* __restrict__ nmagL, float* __restrict__ nmagR){
  int row = blockIdx.x;
  int tid = threadIdx.x;
  __shared__ float gs[HID];
  __shared__ float post[MLPD];
  if (tid < HID) gs[tid] = gout[(size_t)row*HID + tid];
  __syncthreads();
  {
    const float* wp = Wpo + tid*HID;
    float acc = bpo[tid];
    #pragma unroll 8
    for (int i=0;i<HID;i++) acc = fmaf(gs[i], wp[i], acc);
    post[tid] = fmaxf(acc, 0.0f);
  }
  __syncthreads();
  #pragma unroll
  for (int rr=0;rr<3;rr++){
    int c = tid + rr*128;
    if (c >= 323) break;
    const float* W; const float* bb; float* o; int oc, ow; bool sp=false;
    if (c < 32)      { W=WhL; bb=bhL; o=harmL; oc=c;     ow=32; }
    else if (c < 64) { W=WhR; bb=bhR; o=harmR; oc=c-32;  ow=32; }
    else if (c == 64){ W=Wam; bb=bam; o=amp;   oc=0;     ow=1; sp=true; }
    else if (c < 194){ W=WnL; bb=bnL; o=nmagL; oc=c-65;  ow=129; }
    else             { W=WnR; bb=bnR; o=nmagR; oc=c-194; ow=129; }
    const float* wp = W + oc*MLPD;
    float acc = bb[oc];
    #pragma unroll 8
    for (int i=0;i<MLPD;i++) acc = fmaf(post[i], wp[i], acc);
    float v;
    if (sp) v = fmaxf(acc, 0.0f) + log1pf(expf(-fabsf(acc)));
    else    v = 1.0f/(1.0f+expf(-acc));
    o[(size_t)row*ow + oc] = v;
  }
}

// ---------------- mag filter + irfft + window (IN-PLACE on spec slot) ----------------
__global__ __launch_bounds__(256) void k_istft(float* __restrict__ ws){
  int fr = blockIdx.x;
  int ch = blockIdx.y;
  int b = fr / NFRAMES, f = fr - b*NFRAMES;
  float* spec = ws + (ch ? OFF_SPECR : OFF_SPECL) + (size_t)fr*258;
  const float* nmag = ws + (ch ? OFF_NMAGR : OFF_NMAGL) + (size_t)b*TT*NBIN;
  int t = threadIdx.x;
  __shared__ float2 tw[256];
  __shared__ float2 mx[NBIN];
  double a = (2.0*M_PI/256.0)*(double)t;
  float cz = (float)cos(a), sz = (float)sin(a);
  tw[t] = make_float2(cz, sz);
  if (t < NBIN){
    float pos = ((float)f + 0.5f) * R_MAG - 0.5f;
    pos = fminf(fmaxf(pos, 0.0f), 499.0f);
    int i0 = (int)pos, i1 = min(i0+1, TT-1);
    float w = pos - (float)i0;
    float mg = nmag[i0*NBIN + t]*(1.0f-w) + nmag[i1*NBIN + t]*w;
    mx[t] = make_float2(spec[2*t]*mg, spec[2*t+1]*mg);
  }
  __syncthreads();
  float acc0 = mx[0].x + ((t&1) ? -mx[128].x : mx[128].x);
  float acc = 0.0f;
  int mi = t;
  #pragma unroll 4
  for (int k=1;k<128;k++){
    float2 v = mx[k];
    float2 tk = tw[mi];
    acc = fmaf(v.x, tk.x, acc);
    acc = fmaf(-v.y, tk.y, acc);
    mi = (mi + t) & 255;
  }
  float y = (acc0 + 2.0f*acc) * (1.0f/256.0f);
  float win = 0.5f - 0.5f*cz;
  spec[t] = y*win;
}

// ---------------- final: harmonic synth + OLA gather ----------------
__global__ __launch_bounds__(256) void k_out(const float* __restrict__ f0,
    const float* __restrict__ ws, float* __restrict__ out){
  __shared__ float win2[256];
  __shared__ float c1s[BB*32];
  {
    int t = threadIdx.x;
    double a = (2.0*M_PI/256.0)*(double)t;
    float w = (float)(0.5 - 0.5*cos(a));
    win2[t] = w*w;
    if (t < BB*32) c1s[t] = ws[OFF_C1 + t];
  }
  __syncthreads();
  int idx = blockIdx.x*256 + threadIdx.x;
  if (idx >= BB*2*NSAMP) return;
  int m = idx % NSAMP;
  int bc = idx / NSAMP;
  int ch = bc & 1, b = bc >> 1;
  int i0,i1; float w,w1;
  up_coords(m,&i0,&i1,&w,&w1);
  const float* f0b = f0 + b*TT;
  float f0u = __fadd_rn(__fmul_rn(f0b[i0], w1), __fmul_rn(f0b[i1], w));
  const float* am = ws + OFF_AMP + b*TT;
  float oa = __fadd_rn(__fmul_rn(am[i0], w1), __fmul_rn(am[i1], w));
  const float* ha = ws + (ch ? OFF_HARMR : OFF_HARML) + (size_t)b*TT*NHARM;
  float tm = (float)m;
  float hsum = 0.0f;
  for (int k=1;k<=NHARM;k++){
    float instf = __fmul_rn(f0u, (float)k);
    if (instf < 21600.0f){
      float a0 = ha[i0*NHARM + (k-1)], a1 = ha[i1*NHARM + (k-1)];
      float ak = __fadd_rn(__fmul_rn(a0, w1), __fmul_rn(a1, w));
      float ph = __fmul_rn(c1s[b*32 + (k-1)], tm);
      double rev = (double)ph * 0.15915494309189535;
      double fr2 = rev - floor(rev);
      float rad = (float)((fr2 - (fr2 >= 0.5 ? 1.0 : 0.0)) * 6.283185307179586);
      float s = sinf(rad);
      hsum = __fadd_rn(hsum, __fmul_rn(ak, s));
    }
  }
  float harm = __fmul_rn(hsum, oa);
  int p = m + 128;
  int fhi = min(p >> 6, NFRAMES-1);
  int flo = max((p - 192) >> 6, 0);
  const float* frb = ws + (ch ? OFF_SPECR : OFF_SPECL) + (size_t)b*NFRAMES*258;
  float nacc = 0.0f, wsum = 0.0f;
  for (int f=flo; f<=fhi; f++){
    int n = p - f*NHOPF;
    nacc += frb[f*258 + n];
    wsum += win2[n];
  }
  float noise = nacc / fmaxf(wsum, 1e-11f);
  out[idx] = __fadd_rn(harm, noise);
}

extern "C" void kernel_launch(void* const* d_in, const int* in_sizes, int n_in,
                              void* d_out, int out_size, void* d_ws, size_t ws_size,
                              hipStream_t stream){
  const float* f0  = (const float*)d_in[0];
  const float* ldb = (const float*)d_in[1];
  const float* vel = (const float*)d_in[2];
  const float* nL  = (const float*)d_in[3];
  const float* nR  = (const float*)d_in[4];
  const float* Wp1 = (const float*)d_in[5];
  const float* bp1 = (const float*)d_in[6];
  const float* Wp2 = (const float*)d_in[7];
  const float* bp2 = (const float*)d_in[8];
  const float* Wih = (const float*)d_in[9];
  const float* Whh = (const float*)d_in[10];
  const float* bih = (const float*)d_in[11];
  const float* bhh = (const float*)d_in[12];
  const float* Wpo = (const float*)d_in[13];
  const float* bpo = (const float*)d_in[14];
  const float* WhL = (const float*)d_in[15];
  const float* bhL = (const float*)d_in[16];
  const float* WhR = (const float*)d_in[17];
  const float* bhR = (const float*)d_in[18];
  const float* Wam = (const float*)d_in[19];
  const float* bam = (const float*)d_in[20];
  const float* WnL = (const float*)d_in[21];
  const float* bnL = (const float*)d_in[22];
  const float* WnR = (const float*)d_in[23];
  const float* bnR = (const float*)d_in[24];
  float* ws = (float*)d_ws;
  float* out = (float*)d_out;

  k_encmm<<<BB*TT, 128, 0, stream>>>(f0, ldb, vel, Wp1, bp1, ws+OFF_H1);
  k_mm2gi<<<BB*TT, 192, 0, stream>>>(ws+OFF_H1, Wp2, bp2, Wih, bih, ws+OFF_GI);
  k_mid<<<MID_BLOCKS, 384, 0, stream>>>(ws+OFF_GI, Whh, bhh, ws+OFF_GOUT, f0, nL, nR, ws);
  k_posthead<<<BB*TT, 128, 0, stream>>>(ws+OFF_GOUT, Wpo, bpo,
      WhL,bhL, WhR,bhR, Wam,bam, WnL,bnL, WnR,bnR,
      ws+OFF_HARML, ws+OFF_HARMR, ws+OFF_AMP, ws+OFF_NMAGL, ws+OFF_NMAGR);
  dim3 gs(BB*NFRAMES, 2);
  k_istft<<<gs, 256, 0, stream>>>(ws);
  k_out<<<(BB*2*NSAMP+255)/256, 256, 0, stream>>>(f0, ws, out);
}

// Round 13
// 539.839 us; speedup vs baseline: 1.4327x; 1.0365x over previous
//
#include <hip/hip_runtime.h>
#include <math.h>

#ifndef M_PI
#define M_PI 3.14159265358979323846
#endif

#define BB 4
#define TT 500
#define NSAMP 120000
#define NHARM 32
#define NFFT 256
#define NBIN 129
#define NHOPF 64
#define NFRAMES 1876
#define HID 64
#define MLPD 128
#define FEATD 88

#define R_MAG ((float)(500.0/1876.0))
#define R_UP_F ((float)(500.0/120000.0))

// ---- workspace layout (float offsets) ----
#define OFF_HARML 0
#define OFF_HARMR 64000
#define OFF_AMP   128000
#define OFF_NMAGL 130000
#define OFF_NMAGR 388000
#define OFF_C1    646000
#define OFF_H1    646128
#define OFF_GI    (OFF_H1+256000)
#define OFF_GOUT  (OFF_GI+384000)
#define OFF_SPECL (OFF_GOUT+128000)
#define OFF_SPECR (OFF_SPECL+4*NFRAMES*258)
/* end = 5286160 floats = 21.1 MB */

// f32 upsample position/interp chain, bit-exact to numpy float32 elementwise
__device__ __forceinline__ void up_coords(int m, int* i0, int* i1, float* w, float* w1){
  float pos = __fadd_rn(__fmul_rn(__fadd_rn((float)m, 0.5f), R_UP_F), -0.5f);
  pos = fminf(fmaxf(pos, 0.0f), 499.0f);
  int a = (int)pos;
  *i0 = a; *i1 = min(a+1, TT-1);
  float ww = __fsub_rn(pos, (float)a);
  *w = ww; *w1 = __fsub_rn(1.0f, ww);
}
__device__ __forceinline__ float f0_up_elem(const float* __restrict__ f0s, int m){
  int i0,i1; float w,w1;
  up_coords(m,&i0,&i1,&w,&w1);
  return __fadd_rn(__fmul_rn(f0s[i0], w1), __fmul_rn(f0s[i1], w));
}

// ---------------- fused encoding + pre1 matmul ----------------
__global__ __launch_bounds__(128) void k_encmm(const float* __restrict__ f0,
    const float* __restrict__ ldb, const float* __restrict__ vel,
    const float* __restrict__ Wp1, const float* __restrict__ bp1,
    float* __restrict__ h1){
  int row = blockIdx.x;
  int b = row / TT;
  int tid = threadIdx.x;
  __shared__ float feat[FEATD];
  if (tid < FEATD){
    float f = f0[row];
    float gate = (f > 0.0f) ? 1.0f : 0.0f;
    float fs = fmaxf(f, 20.0f);
    float fn = (logf(fs) - (float)2.995732273553991) / (float)5.5214609178622464;
    fn = fminf(fmaxf(fn, 0.0f), 1.0f);
    float ln = fminf(fmaxf((ldb[row] + 80.0f) / 80.0f, 0.0f), 1.0f);
    float vn = fminf(fmaxf(vel[b] / 7.0f, 0.0f), 1.0f);
    float norm; int i; float g2 = 1.0f;
    if (tid < 64){ i = (tid>>1) + 1; norm = fn; g2 = gate; }
    else if (tid < 80){ i = ((tid-64)>>1) + 1; norm = ln; }
    else { i = ((tid-80)>>1) + 1; norm = vn; }
    float ang = (float)M_PI * (float)i * norm;
    feat[tid] = ((tid & 1) ? cosf(ang) : sinf(ang)) * g2;
  }
  __syncthreads();
  const float* wp = Wp1 + tid*FEATD;
  float acc = bp1[tid];
  #pragma unroll 8
  for (int i=0;i<FEATD;i++) acc = fmaf(feat[i], wp[i], acc);
  h1[(size_t)row*MLPD + tid] = fmaxf(acc, 0.0f);
}

// ---------------- fused pre2 matmul + gi matmul ----------------
__global__ __launch_bounds__(192) void k_mm2gi(const float* __restrict__ h1,
    const float* __restrict__ Wp2, const float* __restrict__ bp2,
    const float* __restrict__ Wih, const float* __restrict__ bih,
    float* __restrict__ gi){
  int row = blockIdx.x;
  int tid = threadIdx.x;
  __shared__ float h1s[MLPD];
  __shared__ float h2s[MLPD];
  if (tid < MLPD) h1s[tid] = h1[(size_t)row*MLPD + tid];
  __syncthreads();
  if (tid < MLPD){
    const float* wp = Wp2 + tid*MLPD;
    float acc = bp2[tid];
    #pragma unroll 8
    for (int i=0;i<MLPD;i++) acc = fmaf(h1s[i], wp[i], acc);
    h2s[tid] = fmaxf(acc, 0.0f);
  }
  __syncthreads();
  const float* wp = Wih + tid*MLPD;
  float acc = bih[tid];
  #pragma unroll 8
  for (int i=0;i<MLPD;i++) acc = fmaf(h2s[i], wp[i], acc);
  gi[(size_t)row*192 + tid] = acc;
}

// numpy-exact pairwise block sum (leaf of the depth-10 perfect tree)
__device__ float np_block_sum(const float* __restrict__ f0s, int off, int n, float kf){
  float r[8];
  #pragma unroll
  for (int j=0;j<8;j++) r[j] = __fmul_rn(f0_up_elem(f0s, off+j), kf);
  int lim = n - (n & 7);
  int i = 8;
  for (; i<lim; i+=8){
    #pragma unroll
    for (int j=0;j<8;j++)
      r[j] = __fadd_rn(r[j], __fmul_rn(f0_up_elem(f0s, off+i+j), kf));
  }
  float res = __fadd_rn(__fadd_rn(__fadd_rn(r[0],r[1]), __fadd_rn(r[2],r[3])),
                        __fadd_rn(__fadd_rn(r[4],r[5]), __fadd_rn(r[6],r[7])));
  for (; i<n; i++)
    res = __fadd_rn(res, __fmul_rn(f0_up_elem(f0s, off+i), kf));
  return res;
}

// ---------------- fused mid: GRU + STFT + meanf0 ----------------
#define MID_GRU   BB
#define MID_MF    (MID_GRU + BB*32)
#define STFT_JOBS (2*BB*NFRAMES)
#define MID_STFT_BLOCKS ((STFT_JOBS+5)/6)
#define MID_BLOCKS (MID_MF + MID_STFT_BLOCKS)

#define RL(x,l) __uint_as_float(__builtin_amdgcn_readlane(__float_as_uint(x), (l)))

#define CH  25     /* GRU steps per gi chunk */
#define NCH 20     /* 20*25 = 500 */

__global__ __launch_bounds__(384) void k_mid(
    const float* __restrict__ gi, const float* __restrict__ Whh,
    const float* __restrict__ bhh, float* __restrict__ gout,
    const float* __restrict__ f0, const float* __restrict__ nL,
    const float* __restrict__ nR, float* __restrict__ ws){
  // union LDS: GRU needs gi dbuf 2*25*192=9600 + hist 4096 = 13696 floats (54.8KB)
  __shared__ __align__(16) float sh[13696];
  int blk = blockIdx.x;
  int tid = threadIdx.x;

  if (blk < MID_GRU){
    // ---- GRU: consumer wave (tid<64) runs the recurrence with gi served
    // from LDS; 3 producer waves (tid>=64) double-buffer gi chunks from HBM
    // one chunk ahead. r4-r12 post-mortem: EVERY variant serialized on one
    // HBM round-trip (~900cyc) per step for the in-loop gi loads (FETCH ~
    // 857KB = gi first-touch; 4 GB/s = 768B/690ns). LDS staging takes gi
    // latency off the recurrence entirely; barriers only at chunk bounds
    // (20, not 500). Dot+activations verbatim r12 -> bit-identical gout.
    float* gibuf = sh;            // [2][4800]
    float* hist  = sh + 9600;     // [64][64]
    int b = blk;
    int j = tid & 63;
    float wr[64], wz[64], wn[64];
    float br=0.f, bz=0.f, bn=0.f;
    if (tid < 64){
      #pragma unroll
      for (int i=0;i<16;i++){
        float4 a = *(const float4*)(Whh + (size_t)(j)*64     + i*4);
        float4 c = *(const float4*)(Whh + (size_t)(64+j)*64  + i*4);
        float4 d = *(const float4*)(Whh + (size_t)(128+j)*64 + i*4);
        wr[4*i]=a.x; wr[4*i+1]=a.y; wr[4*i+2]=a.z; wr[4*i+3]=a.w;
        wz[4*i]=c.x; wz[4*i+1]=c.y; wz[4*i+2]=c.z; wz[4*i+3]=c.w;
        wn[4*i]=d.x; wn[4*i+1]=d.y; wn[4*i+2]=d.z; wn[4*i+3]=d.w;
      }
      br = bhh[j]; bz = bhh[64+j]; bn = bhh[128+j];
    }
    const float* gbase = gi + (size_t)b*TT*192;
    // stage chunk 0
    if (tid >= 64){
      int pt = tid - 64;
      for (int idx = pt; idx < CH*48; idx += 192){
        float4 v = *(const float4*)(gbase + idx*4);
        *(float4*)&gibuf[idx*4] = v;
      }
    }
    __syncthreads();
    float hreg = 0.0f;
    float* op = gout + (size_t)b*TT*64;
    for (int c=0; c<NCH; c++){
      if (tid >= 64){
        if (c+1 < NCH){
          int pt = tid - 64;
          const float* src = gbase + (size_t)(c+1)*CH*192;
          float* dst = &gibuf[((c+1)&1)*4800];
          for (int idx = pt; idx < CH*48; idx += 192){
            float4 v = *(const float4*)(src + idx*4);
            *(float4*)&dst[idx*4] = v;
          }
        }
      } else {
        const float* gch = &gibuf[(c&1)*4800];
        for (int tt=0; tt<CH; tt++){
          int t = c*CH + tt;
          float gr0 = gch[tt*192 + j];
          float gz0 = gch[tt*192 + 64 + j];
          float gn0 = gch[tt*192 + 128 + j];
          float ar0=0.f,ar1=0.f,ar2=0.f,ar3=0.f;
          float az0=0.f,az1=0.f,az2=0.f,az3=0.f;
          float an0=0.f,an1=0.f,an2=0.f,an3=0.f;
          #pragma unroll
          for (int i=0;i<16;i++){
            float h0 = RL(hreg, i), h1v = RL(hreg, 16+i);
            float h2v = RL(hreg, 32+i), h3v = RL(hreg, 48+i);
            ar0 = fmaf(wr[i],    h0,  ar0); ar1 = fmaf(wr[16+i], h1v, ar1);
            ar2 = fmaf(wr[32+i], h2v, ar2); ar3 = fmaf(wr[48+i], h3v, ar3);
            az0 = fmaf(wz[i],    h0,  az0); az1 = fmaf(wz[16+i], h1v, az1);
            az2 = fmaf(wz[32+i], h2v, az2); az3 = fmaf(wz[48+i], h3v, az3);
            an0 = fmaf(wn[i],    h0,  an0); an1 = fmaf(wn[16+i], h1v, an1);
            an2 = fmaf(wn[32+i], h2v, an2); an3 = fmaf(wn[48+i], h3v, an3);
          }
          float ar = __fadd_rn(__fadd_rn(ar0,ar1), __fadd_rn(ar2,ar3));
          float az = __fadd_rn(__fadd_rn(az0,az1), __fadd_rn(az2,az3));
          float an = __fadd_rn(__fadd_rn(an0,an1), __fadd_rn(an2,an3));
          float r = 1.0f/(1.0f+expf(-(gr0+ar+br)));
          float z = 1.0f/(1.0f+expf(-(gz0+az+bz)));
          float n = tanhf(gn0 + r*(an+bn));
          hreg = (1.0f - z)*n + z*hreg;
          int th = t & 63;
          hist[th*64 + j] = hreg;
          if (th == 63 || t == TT-1){
            int base_t = t - th;
            int per = th + 1;
            int nb = per >> 2;
            float* dst2 = op + base_t*64 + j*per;
            for (int q=0;q<nb;q++){
              float4 v = *(float4*)&hist[j*per + q*4];
              *(float4*)&dst2[q*4] = v;
            }
          }
        }
      }
      __syncthreads();
    }
  } else if (blk < MID_MF){
    // ---- meanf0 (bit-exact numpy pairwise tree)
    int bk = blk - MID_GRU;
    int b = bk >> 5, k = bk & 31;
    float kf = (float)(k+1);
    float* f0s = sh;
    float* red = sh + 512;
    for (int i=tid;i<TT;i+=384) f0s[i] = f0[b*TT+i];
    __syncthreads();
    if (tid < 256){
      float lv[4];
      #pragma unroll
      for (int q=0;q<4;q++){
        int leafIdx = tid*4 + q;
        int off = 0, n = NSAMP;
        #pragma unroll
        for (int lvl=9; lvl>=0; --lvl){
          int n2 = (n>>1); n2 -= (n2 & 7);
          if ((leafIdx >> lvl) & 1){ off += n2; n -= n2; } else { n = n2; }
        }
        lv[q] = np_block_sum(f0s, off, n, kf);
      }
      red[tid] = __fadd_rn(__fadd_rn(lv[0],lv[1]), __fadd_rn(lv[2],lv[3]));
    }
    __syncthreads();
    for (int cnt=256; cnt>1; cnt>>=1){
      int half = cnt>>1;
      float v = 0.0f;
      if (tid < half) v = __fadd_rn(red[2*tid], red[2*tid+1]);
      __syncthreads();
      if (tid < half) red[tid] = v;
      __syncthreads();
    }
    if (tid==0){
      float mf = __fdiv_rn(red[0], 120000.0f);
      float c1 = __fmul_rn((float)(2.0*M_PI/48000.0), mf);
      ws[OFF_C1 + b*32 + k] = c1;
    }
  } else {
    // ---- STFT: 6 frames per block (one wave each), shared twiddle table
    int base = (blk - MID_MF)*6;
    int sub = tid >> 6;
    int j = tid & 63;
    float2* tw = (float2*)sh;
    float* frs = sh + 512 + sub*256;
    if (tid < 256){
      double a = (2.0*M_PI/256.0)*(double)tid;
      tw[tid] = make_float2((float)cos(a), (float)sin(a));
    }
    int jid = base + sub;
    bool act = jid < STFT_JOBS;
    int b=0, f=0; const float* x = nL;
    if (act){
      int ch = jid / (BB*NFRAMES);
      int rem = jid - ch*(BB*NFRAMES);
      b = rem / NFRAMES; f = rem - b*NFRAMES;
      x = (ch ? nR : nL) + (size_t)b*NSAMP;
      for (int n=j;n<256;n+=64){
        double a = (2.0*M_PI/256.0)*(double)n;
        int xi = f*NHOPF + n - 128;
        xi = xi < 0 ? -xi : xi;
        xi = xi >= NSAMP ? 2*(NSAMP-1)-xi : xi;
        float wnd = (float)(0.5 - 0.5*cos(a));
        frs[n] = x[xi]*wnd;
      }
    }
    __syncthreads();
    if (act){
      int ch = jid / (BB*NFRAMES);
      float* spec = ws + (ch ? OFF_SPECR : OFF_SPECL) + (size_t)(b*NFRAMES+f)*258;
      float re0=0.f, im0=0.f, re1=0.f, im1=0.f;
      int m0 = 0;
      #pragma unroll 4
      for (int n=0;n<256;n++){
        float fv = frs[n];
        int m1 = (m0 + ((n&3)<<6)) & 255;
        float2 t0 = tw[m0], t1 = tw[m1];
        re0 = fmaf(fv, t0.x, re0); im0 = fmaf(-fv, t0.y, im0);
        re1 = fmaf(fv, t1.x, re1); im1 = fmaf(-fv, t1.y, im1);
        m0 = (m0 + j) & 255;
      }
      float pq = frs[j] + frs[j+64] + frs[j+128] + frs[j+192];
      pq = (j & 1) ? -pq : pq;
      for (int o2=32;o2>0;o2>>=1) pq += __shfl_down(pq, o2, 64);
      spec[2*j]   = re0; spec[2*j+1]   = im0;
      spec[2*(j+64)] = re1; spec[2*(j+64)+1] = im1;
      if (j==0){ spec[256] = pq; spec[257] = 0.0f; }
    }
  }
}

// ---------------- fused post matmul + heads ----------------
__global__ __launch_bounds__(128) void k_posthead(const float* __restrict__ gout,
  const float* __restrict__ Wpo, const float* __restrict__ bpo,
  const float* __restrict__ WhL, const float* __restrict__ bhL,
  const float* __restrict__ WhR, const float* __restrict__ bhR,
  const float* __restrict__ Wam, const float* __restrict__ bam,
  const float* __restrict__ WnL, const float* __restrict__ bnL,
  const float* __restrict__ WnR, const float* __restrict__ bnR,
  float* __restrict__ harmL, float* __restrict__ harmR, float* __restrict__ amp,
  float* __restrict__ nmagL, float* __restrict__ nmagR){
  int row = blockIdx.x;
  int tid = threadIdx.x;
  __shared__ float gs[HID];
  __shared__ float post[MLPD];
  if (tid < HID) gs[tid] = gout[(size_t)row*HID + tid];
  __syncthreads();
  {
    const float* wp = Wpo + tid*HID;
    float acc = bpo[tid];
    #pragma unroll 8
    for (int i=0;i<HID;i++) acc = fmaf(gs[i], wp[i], acc);
    post[tid] = fmaxf(acc, 0.0f);
  }
  __syncthreads();
  #pragma unroll
  for (int rr=0;rr<3;rr++){
    int c = tid + rr*128;
    if (c >= 323) break;
    const float* W; const float* bb; float* o; int oc, ow; bool sp=false;
    if (c < 32)      { W=WhL; bb=bhL; o=harmL; oc=c;     ow=32; }
    else if (c < 64) { W=WhR; bb=bhR; o=harmR; oc=c-32;  ow=32; }
    else if (c == 64){ W=Wam; bb=bam; o=amp;   oc=0;     ow=1; sp=true; }
    else if (c < 194){ W=WnL; bb=bnL; o=nmagL; oc=c-65;  ow=129; }
    else             { W=WnR; bb=bnR; o=nmagR; oc=c-194; ow=129; }
    const float* wp = W + oc*MLPD;
    float acc = bb[oc];
    #pragma unroll 8
    for (int i=0;i<MLPD;i++) acc = fmaf(post[i], wp[i], acc);
    float v;
    if (sp) v = fmaxf(acc, 0.0f) + log1pf(expf(-fabsf(acc)));
    else    v = 1.0f/(1.0f+expf(-acc));
    o[(size_t)row*ow + oc] = v;
  }
}

// ---------------- mag filter + irfft + window (IN-PLACE on spec slot) ----------------
__global__ __launch_bounds__(256) void k_istft(float* __restrict__ ws){
  int fr = blockIdx.x;
  int ch = blockIdx.y;
  int b = fr / NFRAMES, f = fr - b*NFRAMES;
  float* spec = ws + (ch ? OFF_SPECR : OFF_SPECL) + (size_t)fr*258;
  const float* nmag = ws + (ch ? OFF_NMAGR : OFF_NMAGL) + (size_t)b*TT*NBIN;
  int t = threadIdx.x;
  __shared__ float2 tw[256];
  __shared__ float2 mx[NBIN];
  double a = (2.0*M_PI/256.0)*(double)t;
  float cz = (float)cos(a), sz = (float)sin(a);
  tw[t] = make_float2(cz, sz);
  if (t < NBIN){
    float pos = ((float)f + 0.5f) * R_MAG - 0.5f;
    pos = fminf(fmaxf(pos, 0.0f), 499.0f);
    int i0 = (int)pos, i1 = min(i0+1, TT-1);
    float w = pos - (float)i0;
    float mg = nmag[i0*NBIN + t]*(1.0f-w) + nmag[i1*NBIN + t]*w;
    mx[t] = make_float2(spec[2*t]*mg, spec[2*t+1]*mg);
  }
  __syncthreads();
  float acc0 = mx[0].x + ((t&1) ? -mx[128].x : mx[128].x);
  float acc = 0.0f;
  int mi = t;
  #pragma unroll 4
  for (int k=1;k<128;k++){
    float2 v = mx[k];
    float2 tk = tw[mi];
    acc = fmaf(v.x, tk.x, acc);
    acc = fmaf(-v.y, tk.y, acc);
    mi = (mi + t) & 255;
  }
  float y = (acc0 + 2.0f*acc) * (1.0f/256.0f);
  float win = 0.5f - 0.5f*cz;
  spec[t] = y*win;
}

// ---------------- final: harmonic synth + OLA gather ----------------
__global__ __launch_bounds__(256) void k_out(const float* __restrict__ f0,
    const float* __restrict__ ws, float* __restrict__ out){
  __shared__ float win2[256];
  __shared__ float c1s[BB*32];
  {
    int t = threadIdx.x;
    double a = (2.0*M_PI/256.0)*(double)t;
    float w = (float)(0.5 - 0.5*cos(a));
    win2[t] = w*w;
    if (t < BB*32) c1s[t] = ws[OFF_C1 + t];
  }
  __syncthreads();
  int idx = blockIdx.x*256 + threadIdx.x;
  if (idx >= BB*2*NSAMP) return;
  int m = idx % NSAMP;
  int bc = idx / NSAMP;
  int ch = bc & 1, b = bc >> 1;
  int i0,i1; float w,w1;
  up_coords(m,&i0,&i1,&w,&w1);
  const float* f0b = f0 + b*TT;
  float f0u = __fadd_rn(__fmul_rn(f0b[i0], w1), __fmul_rn(f0b[i1], w));
  const float* am = ws + OFF_AMP + b*TT;
  float oa = __fadd_rn(__fmul_rn(am[i0], w1), __fmul_rn(am[i1], w));
  const float* ha = ws + (ch ? OFF_HARMR : OFF_HARML) + (size_t)b*TT*NHARM;
  float tm = (float)m;
  float hsum = 0.0f;
  for (int k=1;k<=NHARM;k++){
    float instf = __fmul_rn(f0u, (float)k);
    if (instf < 21600.0f){
      float a0 = ha[i0*NHARM + (k-1)], a1 = ha[i1*NHARM + (k-1)];
      float ak = __fadd_rn(__fmul_rn(a0, w1), __fmul_rn(a1, w));
      float ph = __fmul_rn(c1s[b*32 + (k-1)], tm);
      double rev = (double)ph * 0.15915494309189535;
      double fr2 = rev - floor(rev);
      float rad = (float)((fr2 - (fr2 >= 0.5 ? 1.0 : 0.0)) * 6.283185307179586);
      float s = sinf(rad);
      hsum = __fadd_rn(hsum, __fmul_rn(ak, s));
    }
  }
  float harm = __fmul_rn(hsum, oa);
  int p = m + 128;
  int fhi = min(p >> 6, NFRAMES-1);
  int flo = max((p - 192) >> 6, 0);
  const float* frb = ws + (ch ? OFF_SPECR : OFF_SPECL) + (size_t)b*NFRAMES*258;
  float nacc = 0.0f, wsum = 0.0f;
  for (int f=flo; f<=fhi; f++){
    int n = p - f*NHOPF;
    nacc += frb[f*258 + n];
    wsum += win2[n];
  }
  float noise = nacc / fmaxf(wsum, 1e-11f);
  out[idx] = __fadd_rn(harm, noise);
}

extern "C" void kernel_launch(void* const* d_in, const int* in_sizes, int n_in,
                              void* d_out, int out_size, void* d_ws, size_t ws_size,
                              hipStream_t stream){
  const float* f0  = (const float*)d_in[0];
  const float* ldb = (const float*)d_in[1];
  const float* vel = (const float*)d_in[2];
  const float* nL  = (const float*)d_in[3];
  const float* nR  = (const float*)d_in[4];
  const float* Wp1 = (const float*)d_in[5];
  const float* bp1 = (const float*)d_in[6];
  const float* Wp2 = (const float*)d_in[7];
  const float* bp2 = (const float*)d_in[8];
  const float* Wih = (const float*)d_in[9];
  const float* Whh = (const float*)d_in[10];
  const float* bih = (const float*)d_in[11];
  const float* bhh = (const float*)d_in[12];
  const float* Wpo = (const float*)d_in[13];
  const float* bpo = (const float*)d_in[14];
  const float* WhL = (const float*)d_in[15];
  const float* bhL = (const float*)d_in[16];
  const float* WhR = (const float*)d_in[17];
  const float* bhR = (const float*)d_in[18];
  const float* Wam = (const float*)d_in[19];
  const float* bam = (const float*)d_in[20];
  const float* WnL = (const float*)d_in[21];
  const float* bnL = (const float*)d_in[22];
  const float* WnR = (const float*)d_in[23];
  const float* bnR = (const float*)d_in[24];
  float* ws = (float*)d_ws;
  float* out = (float*)d_out;

  k_encmm<<<BB*TT, 128, 0, stream>>>(f0, ldb, vel, Wp1, bp1, ws+OFF_H1);
  k_mm2gi<<<BB*TT, 192, 0, stream>>>(ws+OFF_H1, Wp2, bp2, Wih, bih, ws+OFF_GI);
  k_mid<<<MID_BLOCKS, 384, 0, stream>>>(ws+OFF_GI, Whh, bhh, ws+OFF_GOUT, f0, nL, nR, ws);
  k_posthead<<<BB*TT, 128, 0, stream>>>(ws+OFF_GOUT, Wpo, bpo,
      WhL,bhL, WhR,bhR, Wam,bam, WnL,bnL, WnR,bnR,
      ws+OFF_HARML, ws+OFF_HARMR, ws+OFF_AMP, ws+OFF_NMAGL, ws+OFF_NMAGR);
  dim3 gs(BB*NFRAMES, 2);
  k_istft<<<gs, 256, 0, stream>>>(ws);
  k_out<<<(BB*2*NSAMP+255)/256, 256, 0, stream>>>(f0, ws, out);
}